// Round 2
// baseline (554.988 us; speedup 1.0000x reference)
//
#include <hip/hip_runtime.h>
#include <hip/hip_bf16.h>
#include <stdint.h>

typedef _Float16 f16;
typedef __attribute__((ext_vector_type(8))) _Float16 f16x8;
typedef __attribute__((ext_vector_type(4))) float f32x4;

__device__ __forceinline__ void g2l16(const void* g, void* l) {
  __builtin_amdgcn_global_load_lds(
      (const __attribute__((address_space(1))) uint32_t*)g,
      (__attribute__((address_space(3))) uint32_t*)l, 16, 0, 0);
}

// ---------------- weight transpose + fp32->f16 convert ----------------
// W: K x N (row-major fp32)  ->  Wt: N x K (row-major f16)
__global__ __launch_bounds__(256)
void wconv_kernel(const float* __restrict__ W, f16* __restrict__ Wt, int K, int N)
{
  __shared__ float tile[32][33];
  int n0 = blockIdx.x * 32, k0 = blockIdx.y * 32;
  int tx = threadIdx.x & 31, ty = threadIdx.x >> 5;  // ty 0..7
#pragma unroll
  for (int i = 0; i < 4; ++i)
    tile[ty + 8*i][tx] = W[(size_t)(k0 + ty + 8*i) * N + (n0 + tx)];
  __syncthreads();
#pragma unroll
  for (int i = 0; i < 4; ++i)
    Wt[(size_t)(n0 + ty + 8*i) * K + (k0 + tx)] = (f16)tile[tx][ty + 8*i];
}

// ---------------- scaled = x*lr + x0*lx ; pre = rmsnorm(scaled) ----------------
__global__ __launch_bounds__(256)
void scale_rms_kernel(const float* __restrict__ x, const float* __restrict__ x0,
                      const float* __restrict__ lamR, const float* __restrict__ lamX,
                      float* __restrict__ scaled, f16* __restrict__ pre)
{
  const int C = 1024;
  int row = blockIdx.x, tid = threadIdx.x;
  float lr = lamR[0], lx = lamX[0];
  size_t base = (size_t)row * C;
  float4 xv = ((const float4*)(x + base))[tid];
  float4 zv = ((const float4*)(x0 + base))[tid];
  float4 sv;
  sv.x = xv.x*lr + zv.x*lx;  sv.y = xv.y*lr + zv.y*lx;
  sv.z = xv.z*lr + zv.z*lx;  sv.w = xv.w*lr + zv.w*lx;
  float ss = sv.x*sv.x + sv.y*sv.y + sv.z*sv.z + sv.w*sv.w;
#pragma unroll
  for (int off = 32; off >= 1; off >>= 1) ss += __shfl_xor(ss, off);
  __shared__ float red[4];
  if ((tid & 63) == 0) red[tid >> 6] = ss;
  __syncthreads();
  float tot = red[0] + red[1] + red[2] + red[3];
  float rs = rsqrtf(tot * (1.0f / 1024.0f) + 1e-5f);
  ((float4*)(scaled + base))[tid] = sv;
  f16* p = pre + base + tid * 4;
  p[0] = (f16)(sv.x * rs); p[1] = (f16)(sv.y * rs);
  p[2] = (f16)(sv.z * rs); p[3] = (f16)(sv.w * rs);
}

// ---------------- pre2 = rmsnorm(fp32 in) as f16 ----------------
__global__ __launch_bounds__(256)
void rms_kernel(const float* __restrict__ xin, f16* __restrict__ outp)
{
  const int C = 1024;
  int row = blockIdx.x, tid = threadIdx.x;
  size_t base = (size_t)row * C;
  float4 sv = ((const float4*)(xin + base))[tid];
  float ss = sv.x*sv.x + sv.y*sv.y + sv.z*sv.z + sv.w*sv.w;
#pragma unroll
  for (int off = 32; off >= 1; off >>= 1) ss += __shfl_xor(ss, off);
  __shared__ float red[4];
  if ((tid & 63) == 0) red[tid >> 6] = ss;
  __syncthreads();
  float tot = red[0] + red[1] + red[2] + red[3];
  float rs = rsqrtf(tot * (1.0f / 1024.0f) + 1e-5f);
  f16* p = outp + base + tid * 4;
  p[0] = (f16)(sv.x * rs); p[1] = (f16)(sv.y * rs);
  p[2] = (f16)(sv.z * rs); p[3] = (f16)(sv.w * rs);
}

// ---------------- in-place RoPE + rmsnorm on (B*T, H, 64) f16 ----------------
__global__ __launch_bounds__(256)
void rope_rms_kernel(f16* __restrict__ X, const float* __restrict__ cs,
                     const float* __restrict__ sn)
{
  int ridx = blockIdx.x * 4 + (threadIdx.x >> 6);  // over B*T*H
  int lane = threadIdx.x & 63;
  int h = ridx & 15;         // H = 16
  int bt = ridx >> 4;
  int t = bt & 2047;         // T = 2048
  size_t base = (size_t)bt * 1024 + h * 64;
  float xv = (float)X[base + lane];
  float other = __shfl_xor(xv, 32);
  float rot = (lane < 32) ? -other : other;   // concat([-x2, x1])
  float c = cs[t * 64 + lane], s = sn[t * 64 + lane];
  float y = xv * c + rot * s;
  float ss = y * y;
#pragma unroll
  for (int off = 32; off >= 1; off >>= 1) ss += __shfl_xor(ss, off);
  float r = rsqrtf(ss * (1.0f / 64.0f) + 1e-5f);
  X[base + lane] = (f16)(y * r);
}

// ---------------- GEMM: C[M,N] = A[M,K] @ Bt[N,K]^T, f16 in, fp32 acc ----------------
// EPI 0: f16 out ; EPI 1: f16 relu(v)^2 ; EPI 2: fp32 out = resid + v
// EPI 3: f16 out written transposed per-head: out[(b*16+h)*64+d][t] (T=2048)
template<int EPI>
__global__ __launch_bounds__(256)
void gemm_kernel(const f16* __restrict__ A, const f16* __restrict__ Bt,
                 const float* __restrict__ resid, void* __restrict__ out,
                 int M, int N, int K)
{
  __shared__ __align__(16) f16 As[128 * 32];
  __shared__ __align__(16) f16 Bs[128 * 32];
  const int tid = threadIdx.x;
  const int wave = tid >> 6, lane = tid & 63;
  const int col = lane & 15, quad = lane >> 4;
  const int m0 = blockIdx.y * 128, n0 = blockIdx.x * 128;
  const int wm = (wave >> 1) * 64, wn = (wave & 1) * 64;
  f32x4 acc[4][4] = {};

  const size_t rowb = (size_t)K * 2;
  const char* Agp = (const char*)A  + (size_t)m0 * rowb;
  const char* Bgp = (const char*)Bt + (size_t)n0 * rowb;

  for (int k0 = 0; k0 < K; k0 += 32) {
#pragma unroll
    for (int i = 0; i < 2; ++i) {
      int e = i * 256 + tid;
      int r = e >> 2;
      int cb = (e & 3) << 4;
      int lbase = (i * 256 + wave * 64) << 4;   // wave-uniform; HW adds lane*16
      g2l16(Agp + (size_t)r * rowb + (size_t)k0 * 2 + cb, (char*)As + lbase);
      g2l16(Bgp + (size_t)r * rowb + (size_t)k0 * 2 + cb, (char*)Bs + lbase);
    }
    __syncthreads();
    f16x8 af[4], bf[4];
#pragma unroll
    for (int t = 0; t < 4; ++t)
      af[t] = *(const f16x8*)(As + (wm + t*16 + col) * 32 + quad * 8);
#pragma unroll
    for (int t = 0; t < 4; ++t)
      bf[t] = *(const f16x8*)(Bs + (wn + t*16 + col) * 32 + quad * 8);
#pragma unroll
    for (int mt = 0; mt < 4; ++mt)
#pragma unroll
      for (int nt = 0; nt < 4; ++nt)
        acc[mt][nt] = __builtin_amdgcn_mfma_f32_16x16x32_f16(af[mt], bf[nt], acc[mt][nt], 0, 0, 0);
    __syncthreads();
  }
#pragma unroll
  for (int mt = 0; mt < 4; ++mt) {
#pragma unroll
    for (int nt = 0; nt < 4; ++nt) {
#pragma unroll
      for (int r = 0; r < 4; ++r) {
        int row = m0 + wm + mt * 16 + quad * 4 + r;   // C/D: row = quad*4+reg
        int cc  = n0 + wn + nt * 16 + col;            //      col = lane&15
        size_t idx = (size_t)row * N + cc;
        float v = acc[mt][nt][r];
        if (EPI == 0) {
          ((f16*)out)[idx] = (f16)v;
        } else if (EPI == 1) {
          float tv = v > 0.0f ? v : 0.0f;
          ((f16*)out)[idx] = (f16)(tv * tv);
        } else if (EPI == 2) {
          ((float*)out)[idx] = resid[idx] + v;
        } else {
          int brow = row >> 11, t = row & 2047;       // M index -> (b, t)
          int hh = cc >> 6, dd = cc & 63;             // N index -> (h, d)
          ((f16*)out)[((size_t)((brow * 16 + hh) * 64 + dd)) * 2048 + t] = (f16)v;
        }
      }
    }
  }
}

// ---------------- causal flash attention, hd=64, f16, swizzled LDS ----------------
// Q,K: [b,t,h,d] f16 ; Vt: [b*16+h, d, t] f16 ; O: [b,t,h,d] f16
// Q-tile 128 (wave: 2 x 16 rows), K-tile 64.
// LDS swizzle: 16B block (row, kb) stored at slot kb ^ (row & 7).
__global__ __launch_bounds__(256)
void attn_kernel(const f16* __restrict__ Q, const f16* __restrict__ Kc,
                 const f16* __restrict__ Vt, f16* __restrict__ O)
{
  const int T = 2048, C = 1024;
  __shared__ __align__(16) f16 Ks[64 * 64];
  __shared__ __align__(16) f16 Vs[64 * 64];
  __shared__ __align__(16) f16 Ps[4][32 * 64];
  const int tid = threadIdx.x, wave = tid >> 6, lane = tid & 63;
  const int col = lane & 15, quad = lane >> 4;
  const int bh = blockIdx.y, b = bh >> 4, h = bh & 15;
  const int qt = (int)gridDim.x - 1 - (int)blockIdx.x;  // big blocks dispatch first
  const int q0 = qt * 128;

  const f16* qb = Q  + ((size_t)b * T) * C + h * 64;
  const f16* kb = Kc + ((size_t)b * T) * C + h * 64;
  const f16* vb = Vt + ((size_t)bh * 64) * T;

  // Q fragments (A-operand): row = q0 + wave*32 + mt*16 + col
  f16x8 aq[2][2];
#pragma unroll
  for (int mt = 0; mt < 2; ++mt)
#pragma unroll
    for (int ks = 0; ks < 2; ++ks)
      aq[mt][ks] = *(const f16x8*)(qb + (size_t)(q0 + wave*32 + mt*16 + col) * C + ks*32 + quad*8);

  float m_i[2][4], l_i[2][4];
  f32x4 o_acc[2][4];
#pragma unroll
  for (int mt = 0; mt < 2; ++mt)
#pragma unroll
    for (int r = 0; r < 4; ++r) { m_i[mt][r] = -1e30f; l_i[mt][r] = 0.0f; }
#pragma unroll
  for (int mt = 0; mt < 2; ++mt)
#pragma unroll
    for (int dt = 0; dt < 4; ++dt) o_acc[mt][dt] = (f32x4){0.f,0.f,0.f,0.f};

  const int srow = lane >> 3;                 // row within 8-row staging chunk
  const int sblk = (lane & 7) ^ srow;         // permuted 16B-block index

  const int ntiles = qt * 2 + 2;
  for (int kt = 0; kt < ntiles; ++kt) {
    const int ks0 = kt * 64;
    // stage K [64 keys][64 d] and V^T [64 d][64 keys], swizzled, 16B async
#pragma unroll
    for (int i = 0; i < 2; ++i) {
      int r0 = wave * 8 + 32 * i;
      g2l16(kb + (size_t)(ks0 + r0 + srow) * C + sblk * 8, (char*)Ks + r0 * 128);
      g2l16(vb + (size_t)(r0 + srow) * T + ks0 + sblk * 8, (char*)Vs + r0 * 128);
    }
    __syncthreads();

    // S = Q K^T
    f32x4 s[2][4];
#pragma unroll
    for (int mt = 0; mt < 2; ++mt)
#pragma unroll
      for (int nt = 0; nt < 4; ++nt) s[mt][nt] = (f32x4){0.f,0.f,0.f,0.f};
#pragma unroll
    for (int ks = 0; ks < 2; ++ks) {
#pragma unroll
      for (int nt = 0; nt < 4; ++nt) {
        int key = nt * 16 + col;
        f16x8 bk = *(const f16x8*)(Ks + key * 64 + (((ks*4 + quad) ^ (key & 7)) * 8));
        s[0][nt] = __builtin_amdgcn_mfma_f32_16x16x32_f16(aq[0][ks], bk, s[0][nt], 0, 0, 0);
        s[1][nt] = __builtin_amdgcn_mfma_f32_16x16x32_f16(aq[1][ks], bk, s[1][nt], 0, 0, 0);
      }
    }

    const bool masked = (ks0 + 63 > q0 + wave * 32);  // wave-uniform
    // online softmax per (mt, r)
#pragma unroll
    for (int mt = 0; mt < 2; ++mt) {
#pragma unroll
      for (int r = 0; r < 4; ++r) {
        const int qloc = mt * 16 + quad * 4 + r;
        const int qr = q0 + wave * 32 + qloc;
        float a[4];
#pragma unroll
        for (int nt = 0; nt < 4; ++nt) a[nt] = s[mt][nt][r] * 0.125f;
        if (masked) {
#pragma unroll
          for (int nt = 0; nt < 4; ++nt)
            a[nt] = (ks0 + nt * 16 + col <= qr) ? a[nt] : -1e9f;
        }
        float mx = fmaxf(fmaxf(a[0], a[1]), fmaxf(a[2], a[3]));
#pragma unroll
        for (int off = 8; off >= 1; off >>= 1)
          mx = fmaxf(mx, __shfl_xor(mx, off, 16));
        float mnew = fmaxf(m_i[mt][r], mx);
        float alpha = __expf(m_i[mt][r] - mnew);
        float p[4];
#pragma unroll
        for (int nt = 0; nt < 4; ++nt) p[nt] = __expf(a[nt] - mnew);
        float su = (p[0] + p[1]) + (p[2] + p[3]);
#pragma unroll
        for (int off = 8; off >= 1; off >>= 1)
          su += __shfl_xor(su, off, 16);
        l_i[mt][r] = l_i[mt][r] * alpha + su;
        m_i[mt][r] = mnew;
#pragma unroll
        for (int dt = 0; dt < 4; ++dt) o_acc[mt][dt][r] *= alpha;
        // store P swizzled (per-wave region; same-wave read below)
#pragma unroll
        for (int nt = 0; nt < 4; ++nt) {
          int kblk = nt * 2 + (col >> 3);
          Ps[wave][qloc * 64 + ((kblk ^ (qloc & 7)) * 8) + (col & 7)] = (f16)p[nt];
        }
      }
    }

    // O += P V
#pragma unroll
    for (int ks = 0; ks < 2; ++ks) {
      f16x8 ap0 = *(const f16x8*)(&Ps[wave][0] + (col) * 64      + (((ks*4 + quad) ^ (col & 7)) * 8));
      f16x8 ap1 = *(const f16x8*)(&Ps[wave][0] + (16 + col) * 64 + (((ks*4 + quad) ^ (col & 7)) * 8));
#pragma unroll
      for (int dt = 0; dt < 4; ++dt) {
        int d = dt * 16 + col;
        f16x8 bv = *(const f16x8*)(Vs + d * 64 + (((ks*4 + quad) ^ (d & 7)) * 8));
        o_acc[0][dt] = __builtin_amdgcn_mfma_f32_16x16x32_f16(ap0, bv, o_acc[0][dt], 0, 0, 0);
        o_acc[1][dt] = __builtin_amdgcn_mfma_f32_16x16x32_f16(ap1, bv, o_acc[1][dt], 0, 0, 0);
      }
    }
    __syncthreads();
  }

#pragma unroll
  for (int mt = 0; mt < 2; ++mt) {
#pragma unroll
    for (int dt = 0; dt < 4; ++dt) {
#pragma unroll
      for (int r = 0; r < 4; ++r) {
        int qr = q0 + wave * 32 + mt * 16 + quad * 4 + r;
        float v = o_acc[mt][dt][r] / l_i[mt][r];
        O[((size_t)b * T + qr) * C + h * 64 + dt * 16 + col] = (f16)v;
      }
    }
  }
}

// ---------------- orchestration ----------------
extern "C" void kernel_launch(void* const* d_in, const int* in_sizes, int n_in,
                              void* d_out, int out_size, void* d_ws, size_t ws_size,
                              hipStream_t stream)
{
  const float* x    = (const float*)d_in[0];
  const float* x0   = (const float*)d_in[1];
  const float* lamR = (const float*)d_in[2];
  const float* lamX = (const float*)d_in[3];
  const float* cs   = (const float*)d_in[4];
  const float* sn   = (const float*)d_in[5];
  const float* Wq   = (const float*)d_in[6];
  const float* Wk   = (const float*)d_in[7];
  const float* Wv   = (const float*)d_in[8];
  const float* Wp   = (const float*)d_in[9];
  const float* Wfc  = (const float*)d_in[10];
  const float* Wmp  = (const float*)d_in[11];
  float* out = (float*)d_out;

  const int B = 2, T = 2048, C = 1024, H = 16;
  const int M = B * T;  // 4096
  const size_t MB = 1ull << 20;
  char* ws = (char*)d_ws;
  f16*   Wq_t   = (f16*)(ws + 0 * MB);    // 2 MB each
  f16*   Wk_t   = (f16*)(ws + 2 * MB);
  f16*   Wv_t   = (f16*)(ws + 4 * MB);
  f16*   Wp_t   = (f16*)(ws + 6 * MB);
  f16*   Wfc_t  = (f16*)(ws + 8 * MB);    // 8 MB  (4096 x 1024)
  f16*   Wmp_t  = (f16*)(ws + 16 * MB);   // 8 MB  (1024 x 4096)
  float* scaled  = (float*)(ws + 24 * MB); // 16 MB fp32
  f16*   pre     = (f16*)(ws + 40 * MB);   // 8 MB; reused as attnOut
  f16*   qb      = (f16*)(ws + 48 * MB);   // 8 MB; reused as pre2
  f16*   kbuf    = (f16*)(ws + 56 * MB);   // 8 MB
  f16*   vtg     = (f16*)(ws + 64 * MB);   // 8 MB  V^T as [b*16+h][64][2048]
  float* scaled2 = (float*)(ws + 72 * MB); // 16 MB fp32
  f16*   hbuf    = (f16*)(ws + 88 * MB);   // 32 MB (4096 x 4096 f16)
  f16*   attnOut = pre;
  f16*   pre2    = qb;

  dim3 tb(256);
  // weight convert+transpose (K x N fp32 -> N x K f16)
  wconv_kernel<<<dim3(C/32,   C/32),   tb, 0, stream>>>(Wq,  Wq_t,  C,   C);
  wconv_kernel<<<dim3(C/32,   C/32),   tb, 0, stream>>>(Wk,  Wk_t,  C,   C);
  wconv_kernel<<<dim3(C/32,   C/32),   tb, 0, stream>>>(Wv,  Wv_t,  C,   C);
  wconv_kernel<<<dim3(C/32,   C/32),   tb, 0, stream>>>(Wp,  Wp_t,  C,   C);
  wconv_kernel<<<dim3(4*C/32, C/32),   tb, 0, stream>>>(Wfc, Wfc_t, C,   4*C);
  wconv_kernel<<<dim3(C/32,   4*C/32), tb, 0, stream>>>(Wmp, Wmp_t, 4*C, C);

  scale_rms_kernel<<<M, tb, 0, stream>>>(x, x0, lamR, lamX, scaled, pre);

  gemm_kernel<0><<<dim3(C/128, M/128), tb, 0, stream>>>(pre, Wq_t, nullptr, qb,   M, C, C);
  gemm_kernel<0><<<dim3(C/128, M/128), tb, 0, stream>>>(pre, Wk_t, nullptr, kbuf, M, C, C);
  gemm_kernel<3><<<dim3(C/128, M/128), tb, 0, stream>>>(pre, Wv_t, nullptr, vtg,  M, C, C);

  rope_rms_kernel<<<(M * H) / 4, tb, 0, stream>>>(qb,   cs, sn);
  rope_rms_kernel<<<(M * H) / 4, tb, 0, stream>>>(kbuf, cs, sn);

  attn_kernel<<<dim3(T/128, B * H), tb, 0, stream>>>(qb, kbuf, vtg, attnOut);

  gemm_kernel<2><<<dim3(C/128, M/128), tb, 0, stream>>>(attnOut, Wp_t, scaled, scaled2, M, C, C);

  rms_kernel<<<M, tb, 0, stream>>>(scaled2, pre2);

  gemm_kernel<1><<<dim3(4*C/128, M/128), tb, 0, stream>>>(pre2, Wfc_t, nullptr, hbuf, M, 4*C, C);

  gemm_kernel<2><<<dim3(C/128, M/128), tb, 0, stream>>>(hbuf, Wmp_t, scaled2, out, M, C, 4*C);
}

// Round 3
// 458.500 us; speedup vs baseline: 1.2104x; 1.2104x over previous
//
#include <hip/hip_runtime.h>
#include <hip/hip_bf16.h>
#include <stdint.h>

typedef _Float16 f16;
typedef __attribute__((ext_vector_type(8))) _Float16 f16x8;
typedef __attribute__((ext_vector_type(4))) float f32x4;

__device__ __forceinline__ void g2l16(const void* g, void* l) {
  __builtin_amdgcn_global_load_lds(
      (const __attribute__((address_space(1))) uint32_t*)g,
      (__attribute__((address_space(3))) uint32_t*)l, 16, 0, 0);
}

// ---------------- weight transpose + fp32->f16 convert ----------------
// W: K x N (row-major fp32)  ->  Wt: N x K (row-major f16)
__global__ __launch_bounds__(256)
void wconv_kernel(const float* __restrict__ W, f16* __restrict__ Wt, int K, int N)
{
  __shared__ float tile[32][33];
  int n0 = blockIdx.x * 32, k0 = blockIdx.y * 32;
  int tx = threadIdx.x & 31, ty = threadIdx.x >> 5;  // ty 0..7
#pragma unroll
  for (int i = 0; i < 4; ++i)
    tile[ty + 8*i][tx] = W[(size_t)(k0 + ty + 8*i) * N + (n0 + tx)];
  __syncthreads();
#pragma unroll
  for (int i = 0; i < 4; ++i)
    Wt[(size_t)(n0 + ty + 8*i) * K + (k0 + tx)] = (f16)tile[tx][ty + 8*i];
}

// ---------------- scaled = x*lr + x0*lx ; pre = rmsnorm(scaled) ----------------
__global__ __launch_bounds__(256)
void scale_rms_kernel(const float* __restrict__ x, const float* __restrict__ x0,
                      const float* __restrict__ lamR, const float* __restrict__ lamX,
                      float* __restrict__ scaled, f16* __restrict__ pre)
{
  const int C = 1024;
  int row = blockIdx.x, tid = threadIdx.x;
  float lr = lamR[0], lx = lamX[0];
  size_t base = (size_t)row * C;
  float4 xv = ((const float4*)(x + base))[tid];
  float4 zv = ((const float4*)(x0 + base))[tid];
  float4 sv;
  sv.x = xv.x*lr + zv.x*lx;  sv.y = xv.y*lr + zv.y*lx;
  sv.z = xv.z*lr + zv.z*lx;  sv.w = xv.w*lr + zv.w*lx;
  float ss = sv.x*sv.x + sv.y*sv.y + sv.z*sv.z + sv.w*sv.w;
#pragma unroll
  for (int off = 32; off >= 1; off >>= 1) ss += __shfl_xor(ss, off);
  __shared__ float red[4];
  if ((tid & 63) == 0) red[tid >> 6] = ss;
  __syncthreads();
  float tot = red[0] + red[1] + red[2] + red[3];
  float rs = rsqrtf(tot * (1.0f / 1024.0f) + 1e-5f);
  ((float4*)(scaled + base))[tid] = sv;
  f16* p = pre + base + tid * 4;
  p[0] = (f16)(sv.x * rs); p[1] = (f16)(sv.y * rs);
  p[2] = (f16)(sv.z * rs); p[3] = (f16)(sv.w * rs);
}

// ---------------- combine_rms: scaled2 = resid+p0+p1 ; pre2 = rms(scaled2) f16 ----------------
__global__ __launch_bounds__(256)
void combine_rms_kernel(const float* __restrict__ resid, const float* __restrict__ p0,
                        const float* __restrict__ p1, float* __restrict__ scaled2,
                        f16* __restrict__ pre2)
{
  const int C = 1024;
  int row = blockIdx.x, tid = threadIdx.x;
  size_t base = (size_t)row * C;
  float4 rv = ((const float4*)(resid + base))[tid];
  float4 av = ((const float4*)(p0 + base))[tid];
  float4 bv = ((const float4*)(p1 + base))[tid];
  float4 sv;
  sv.x = rv.x + av.x + bv.x; sv.y = rv.y + av.y + bv.y;
  sv.z = rv.z + av.z + bv.z; sv.w = rv.w + av.w + bv.w;
  float ss = sv.x*sv.x + sv.y*sv.y + sv.z*sv.z + sv.w*sv.w;
#pragma unroll
  for (int off = 32; off >= 1; off >>= 1) ss += __shfl_xor(ss, off);
  __shared__ float red[4];
  if ((tid & 63) == 0) red[tid >> 6] = ss;
  __syncthreads();
  float tot = red[0] + red[1] + red[2] + red[3];
  float rs = rsqrtf(tot * (1.0f / 1024.0f) + 1e-5f);
  ((float4*)(scaled2 + base))[tid] = sv;
  f16* p = pre2 + base + tid * 4;
  p[0] = (f16)(sv.x * rs); p[1] = (f16)(sv.y * rs);
  p[2] = (f16)(sv.z * rs); p[3] = (f16)(sv.w * rs);
}

// ---------------- combine_out: out = resid + p0 + p1 ----------------
__global__ __launch_bounds__(256)
void combine_out_kernel(const float* __restrict__ resid, const float* __restrict__ p0,
                        const float* __restrict__ p1, float* __restrict__ out)
{
  size_t i = (size_t)blockIdx.x * 256 + threadIdx.x;
  float4 rv = ((const float4*)resid)[i];
  float4 av = ((const float4*)p0)[i];
  float4 bv = ((const float4*)p1)[i];
  float4 sv;
  sv.x = rv.x + av.x + bv.x; sv.y = rv.y + av.y + bv.y;
  sv.z = rv.z + av.z + bv.z; sv.w = rv.w + av.w + bv.w;
  ((float4*)out)[i] = sv;
}

// ---------------- in-place RoPE + rmsnorm on (B*T, H, 64) f16 ----------------
__global__ __launch_bounds__(256)
void rope_rms_kernel(f16* __restrict__ X, const float* __restrict__ cs,
                     const float* __restrict__ sn)
{
  int ridx = blockIdx.x * 4 + (threadIdx.x >> 6);  // over B*T*H
  int lane = threadIdx.x & 63;
  int h = ridx & 15;         // H = 16
  int bt = ridx >> 4;
  int t = bt & 2047;         // T = 2048
  size_t base = (size_t)bt * 1024 + h * 64;
  float xv = (float)X[base + lane];
  float other = __shfl_xor(xv, 32);
  float rot = (lane < 32) ? -other : other;   // concat([-x2, x1])
  float c = cs[t * 64 + lane], s = sn[t * 64 + lane];
  float y = xv * c + rot * s;
  float ss = y * y;
#pragma unroll
  for (int off = 32; off >= 1; off >>= 1) ss += __shfl_xor(ss, off);
  float r = rsqrtf(ss * (1.0f / 64.0f) + 1e-5f);
  X[base + lane] = (f16)(y * r);
}

// ---------------- GEMM: C[M,N] = A[M,K] @ Bt[N,K]^T, f16 in, fp32 acc ----------------
// EPI 1: f16 relu(v)^2 ; EPI 4: fp32 partial store at out + z*M*N (split-K via gridDim.z)
template<int EPI>
__global__ __launch_bounds__(256)
void gemm_kernel(const f16* __restrict__ A, const f16* __restrict__ Bt,
                 void* __restrict__ out, int M, int N, int K)
{
  __shared__ __align__(16) f16 As[128 * 32];
  __shared__ __align__(16) f16 Bs[128 * 32];
  const int tid = threadIdx.x;
  const int wave = tid >> 6, lane = tid & 63;
  const int col = lane & 15, quad = lane >> 4;
  const int m0 = blockIdx.y * 128, n0 = blockIdx.x * 128;
  const int wm = (wave >> 1) * 64, wn = (wave & 1) * 64;
  const int Ksub = K / gridDim.z;
  const int kBeg = blockIdx.z * Ksub, kEnd = kBeg + Ksub;
  f32x4 acc[4][4] = {};

  const size_t rowb = (size_t)K * 2;
  const char* Agp = (const char*)A  + (size_t)m0 * rowb;
  const char* Bgp = (const char*)Bt + (size_t)n0 * rowb;

  for (int k0 = kBeg; k0 < kEnd; k0 += 32) {
#pragma unroll
    for (int i = 0; i < 2; ++i) {
      int e = i * 256 + tid;
      int r = e >> 2;
      int cb = (e & 3) << 4;
      int lbase = (i * 256 + wave * 64) << 4;   // wave-uniform; HW adds lane*16
      g2l16(Agp + (size_t)r * rowb + (size_t)k0 * 2 + cb, (char*)As + lbase);
      g2l16(Bgp + (size_t)r * rowb + (size_t)k0 * 2 + cb, (char*)Bs + lbase);
    }
    __syncthreads();
    f16x8 af[4], bf[4];
#pragma unroll
    for (int t = 0; t < 4; ++t)
      af[t] = *(const f16x8*)(As + (wm + t*16 + col) * 32 + quad * 8);
#pragma unroll
    for (int t = 0; t < 4; ++t)
      bf[t] = *(const f16x8*)(Bs + (wn + t*16 + col) * 32 + quad * 8);
#pragma unroll
    for (int mt = 0; mt < 4; ++mt)
#pragma unroll
      for (int nt = 0; nt < 4; ++nt)
        acc[mt][nt] = __builtin_amdgcn_mfma_f32_16x16x32_f16(af[mt], bf[nt], acc[mt][nt], 0, 0, 0);
    __syncthreads();
  }
  float* outz = (EPI == 4) ? ((float*)out + (size_t)blockIdx.z * M * N) : nullptr;
#pragma unroll
  for (int mt = 0; mt < 4; ++mt) {
#pragma unroll
    for (int nt = 0; nt < 4; ++nt) {
#pragma unroll
      for (int r = 0; r < 4; ++r) {
        int row = m0 + wm + mt * 16 + quad * 4 + r;   // C/D: row = quad*4+reg
        int cc  = n0 + wn + nt * 16 + col;            //      col = lane&15
        size_t idx = (size_t)row * N + cc;
        float v = acc[mt][nt][r];
        if (EPI == 1) {
          float tv = v > 0.0f ? v : 0.0f;
          ((f16*)out)[idx] = (f16)(tv * tv);
        } else {
          outz[idx] = v;
        }
      }
    }
  }
}

// ---------------- fused QKV GEMM: A[4096,1024] @ Wqkv[3072,1024]^T ----------------
// cols 0..1023 -> qb, 1024..2047 -> kbuf (both [b,t,h,d] f16),
// cols 2048..3071 -> vtg transposed: [(b*16+h)*64+d][t]
__global__ __launch_bounds__(256)
void gemm_qkv_kernel(const f16* __restrict__ A, const f16* __restrict__ Bt,
                     f16* __restrict__ qb, f16* __restrict__ kbuf, f16* __restrict__ vtg)
{
  const int N = 3072, K = 1024;
  __shared__ __align__(16) f16 As[128 * 32];
  __shared__ __align__(16) f16 Bs[128 * 32];
  const int tid = threadIdx.x;
  const int wave = tid >> 6, lane = tid & 63;
  const int col = lane & 15, quad = lane >> 4;
  const int m0 = blockIdx.y * 128, n0 = blockIdx.x * 128;
  const int wm = (wave >> 1) * 64, wn = (wave & 1) * 64;
  f32x4 acc[4][4] = {};

  const size_t rowb = (size_t)K * 2;
  const char* Agp = (const char*)A  + (size_t)m0 * rowb;
  const char* Bgp = (const char*)Bt + (size_t)n0 * rowb;

  for (int k0 = 0; k0 < K; k0 += 32) {
#pragma unroll
    for (int i = 0; i < 2; ++i) {
      int e = i * 256 + tid;
      int r = e >> 2;
      int cb = (e & 3) << 4;
      int lbase = (i * 256 + wave * 64) << 4;
      g2l16(Agp + (size_t)r * rowb + (size_t)k0 * 2 + cb, (char*)As + lbase);
      g2l16(Bgp + (size_t)r * rowb + (size_t)k0 * 2 + cb, (char*)Bs + lbase);
    }
    __syncthreads();
    f16x8 af[4], bf[4];
#pragma unroll
    for (int t = 0; t < 4; ++t)
      af[t] = *(const f16x8*)(As + (wm + t*16 + col) * 32 + quad * 8);
#pragma unroll
    for (int t = 0; t < 4; ++t)
      bf[t] = *(const f16x8*)(Bs + (wn + t*16 + col) * 32 + quad * 8);
#pragma unroll
    for (int mt = 0; mt < 4; ++mt)
#pragma unroll
      for (int nt = 0; nt < 4; ++nt)
        acc[mt][nt] = __builtin_amdgcn_mfma_f32_16x16x32_f16(af[mt], bf[nt], acc[mt][nt], 0, 0, 0);
    __syncthreads();
  }
  const int sel = (n0 + wn) >> 10;   // 0: Q, 1: K, 2: V (wave-uniform)
#pragma unroll
  for (int mt = 0; mt < 4; ++mt) {
#pragma unroll
    for (int nt = 0; nt < 4; ++nt) {
#pragma unroll
      for (int r = 0; r < 4; ++r) {
        int row = m0 + wm + mt * 16 + quad * 4 + r;
        int cc  = n0 + wn + nt * 16 + col;
        float v = acc[mt][nt][r];
        if (sel == 0) {
          qb[(size_t)row * 1024 + (cc & 1023)] = (f16)v;
        } else if (sel == 1) {
          kbuf[(size_t)row * 1024 + (cc & 1023)] = (f16)v;
        } else {
          int b = row >> 11, t = row & 2047;
          int hh = (cc - 2048) >> 6, dd = cc & 63;
          vtg[((size_t)((b * 16 + hh) * 64 + dd)) * 2048 + t] = (f16)v;
        }
      }
    }
  }
}

// ---------------- causal flash attention, hd=64, no-max softmax ----------------
// After rmsnorm ||q||=||k||=8 exactly -> |score| <= 8 -> exp(score) <= e^8 < f16 max.
// So: p = exp(score) directly, no running max, no rescale; l summed per-lane,
// one width-16 reduction per row at the end.
// Q,K: [b,t,h,d] f16 ; Vt: [(b*16+h)*64+d][t] f16 ; O: [b,t,h,d] f16
// Q-tile 64 (wave: 16 rows), K-tile 64, grid (32 qt reversed, 32 bh).
__global__ __launch_bounds__(256)
void attn_kernel(const f16* __restrict__ Q, const f16* __restrict__ Kc,
                 const f16* __restrict__ Vt, f16* __restrict__ O)
{
  const int T = 2048, C = 1024;
  __shared__ __align__(16) f16 Ks[64 * 64];
  __shared__ __align__(16) f16 Vs[64 * 64];
  __shared__ __align__(16) f16 Ps[4][16 * 64];
  const int tid = threadIdx.x, wave = tid >> 6, lane = tid & 63;
  const int col = lane & 15, quad = lane >> 4;
  const int bh = blockIdx.y, b = bh >> 4, h = bh & 15;
  const int qt = (int)gridDim.x - 1 - (int)blockIdx.x;  // big blocks dispatch first
  const int q0 = qt * 64;

  const f16* qb = Q  + ((size_t)b * T) * C + h * 64;
  const f16* kb = Kc + ((size_t)b * T) * C + h * 64;
  const f16* vb = Vt + ((size_t)bh * 64) * T;

  // Q fragments (A-operand): row = q0 + wave*16 + col
  f16x8 aq[2];
#pragma unroll
  for (int ks = 0; ks < 2; ++ks)
    aq[ks] = *(const f16x8*)(qb + (size_t)(q0 + wave*16 + col) * C + ks*32 + quad*8);

  f32x4 o_acc[4];
#pragma unroll
  for (int dt = 0; dt < 4; ++dt) o_acc[dt] = (f32x4){0.f,0.f,0.f,0.f};
  float l_part[4] = {0.f, 0.f, 0.f, 0.f};

  const int srow = lane >> 3;                 // row within 8-row staging chunk
  const int sblk = (lane & 7) ^ srow;         // permuted 16B-block index

  for (int kt = 0; kt <= qt; ++kt) {
    const int ks0 = kt * 64;
    // stage K [64 keys][64 d] and V^T [64 d][64 keys], swizzled, 16B async
#pragma unroll
    for (int i = 0; i < 2; ++i) {
      int r0 = wave * 16 + 8 * i;
      g2l16(kb + (size_t)(ks0 + r0 + srow) * C + sblk * 8, (char*)Ks + r0 * 128);
      g2l16(vb + (size_t)(r0 + srow) * T + ks0 + sblk * 8, (char*)Vs + r0 * 128);
    }
    __syncthreads();

    // S = Q K^T
    f32x4 s[4];
#pragma unroll
    for (int nt = 0; nt < 4; ++nt) s[nt] = (f32x4){0.f,0.f,0.f,0.f};
#pragma unroll
    for (int ks = 0; ks < 2; ++ks) {
#pragma unroll
      for (int nt = 0; nt < 4; ++nt) {
        int key = nt * 16 + col;
        f16x8 bk = *(const f16x8*)(Ks + key * 64 + (((ks*4 + quad) ^ (key & 7)) * 8));
        s[nt] = __builtin_amdgcn_mfma_f32_16x16x32_f16(aq[ks], bk, s[nt], 0, 0, 0);
      }
    }

    const bool masked = (kt == qt);
#pragma unroll
    for (int r = 0; r < 4; ++r) {
      const int qloc = quad * 4 + r;          // row within wave's 16-row tile
      float p[4];
#pragma unroll
      for (int nt = 0; nt < 4; ++nt) {
        float pv = __expf(s[nt][r] * 0.125f);
        if (masked && (nt * 16 + col > wave * 16 + qloc)) pv = 0.0f;
        p[nt] = pv;
      }
      l_part[r] += (p[0] + p[1]) + (p[2] + p[3]);
#pragma unroll
      for (int nt = 0; nt < 4; ++nt) {
        int kblk = nt * 2 + (col >> 3);
        Ps[wave][qloc * 64 + ((kblk ^ (qloc & 7)) * 8) + (col & 7)] = (f16)p[nt];
      }
    }

    // O += P V   (Ps is per-wave; same-wave DS ordering guarantees visibility)
#pragma unroll
    for (int ks = 0; ks < 2; ++ks) {
      f16x8 ap = *(const f16x8*)(&Ps[wave][0] + col * 64 + (((ks*4 + quad) ^ (col & 7)) * 8));
#pragma unroll
      for (int dt = 0; dt < 4; ++dt) {
        int d = dt * 16 + col;
        f16x8 bv = *(const f16x8*)(Vs + d * 64 + (((ks*4 + quad) ^ (d & 7)) * 8));
        o_acc[dt] = __builtin_amdgcn_mfma_f32_16x16x32_f16(ap, bv, o_acc[dt], 0, 0, 0);
      }
    }
    __syncthreads();
  }

  // final row-sum reduction (16 lanes per row)
#pragma unroll
  for (int r = 0; r < 4; ++r) {
#pragma unroll
    for (int off = 8; off >= 1; off >>= 1)
      l_part[r] += __shfl_xor(l_part[r], off, 16);
  }
#pragma unroll
  for (int dt = 0; dt < 4; ++dt) {
#pragma unroll
    for (int r = 0; r < 4; ++r) {
      int qr = q0 + wave * 16 + quad * 4 + r;
      float v = o_acc[dt][r] / l_part[r];
      O[((size_t)b * T + qr) * C + h * 64 + dt * 16 + col] = (f16)v;
    }
  }
}

// ---------------- orchestration ----------------
extern "C" void kernel_launch(void* const* d_in, const int* in_sizes, int n_in,
                              void* d_out, int out_size, void* d_ws, size_t ws_size,
                              hipStream_t stream)
{
  const float* x    = (const float*)d_in[0];
  const float* x0   = (const float*)d_in[1];
  const float* lamR = (const float*)d_in[2];
  const float* lamX = (const float*)d_in[3];
  const float* cs   = (const float*)d_in[4];
  const float* sn   = (const float*)d_in[5];
  const float* Wq   = (const float*)d_in[6];
  const float* Wk   = (const float*)d_in[7];
  const float* Wv   = (const float*)d_in[8];
  const float* Wp   = (const float*)d_in[9];
  const float* Wfc  = (const float*)d_in[10];
  const float* Wmp  = (const float*)d_in[11];
  float* out = (float*)d_out;

  const int B = 2, T = 2048, C = 1024, H = 16;
  const int M = B * T;  // 4096
  const size_t MB = 1ull << 20;
  char* ws = (char*)d_ws;
  f16*   Wqkv_t = (f16*)(ws + 0 * MB);     // 6 MB: Wq|Wk|Wv each [1024][1024] f16
  f16*   Wp_t   = (f16*)(ws + 6 * MB);     // 2 MB
  f16*   Wfc_t  = (f16*)(ws + 8 * MB);     // 8 MB  (4096 x 1024)
  f16*   Wmp_t  = (f16*)(ws + 16 * MB);    // 8 MB  (1024 x 4096)
  float* scaled  = (float*)(ws + 24 * MB); // 16 MB fp32   [reused: mlp partial 0]
  f16*   pre     = (f16*)(ws + 40 * MB);   // 8 MB         [reused: attnOut]
  f16*   qb      = (f16*)(ws + 48 * MB);   // 8 MB         [reused: pre2]
  f16*   kbuf    = (f16*)(ws + 56 * MB);   // 8 MB         [reused: mlp partial 1 lo]
  f16*   vtg     = (f16*)(ws + 64 * MB);   // 8 MB V^T     [reused: mlp partial 1 hi]
  float* scaled2 = (float*)(ws + 72 * MB); // 16 MB fp32
  f16*   hbuf    = (f16*)(ws + 88 * MB);   // 32 MB (4096x4096 f16) [first: proj partials]
  f16*   attnOut = pre;
  f16*   pre2    = qb;
  float* projP   = (float*)(ws + 88 * MB); // 2 x 16 MB fp32 (before hbuf is written)
  float* mlpP0   = (float*)(ws + 24 * MB); // scaled region (free after combine_rms)
  float* mlpP1   = (float*)(ws + 56 * MB); // kbuf+vtg region (free after attn)

  dim3 tb(256);
  // weight convert+transpose (K x N fp32 -> N x K f16)
  wconv_kernel<<<dim3(C/32,   C/32),   tb, 0, stream>>>(Wq,  Wqkv_t,             C,   C);
  wconv_kernel<<<dim3(C/32,   C/32),   tb, 0, stream>>>(Wk,  Wqkv_t + 1024*1024, C,   C);
  wconv_kernel<<<dim3(C/32,   C/32),   tb, 0, stream>>>(Wv,  Wqkv_t + 2048*1024, C,   C);
  wconv_kernel<<<dim3(C/32,   C/32),   tb, 0, stream>>>(Wp,  Wp_t,               C,   C);
  wconv_kernel<<<dim3(4*C/32, C/32),   tb, 0, stream>>>(Wfc, Wfc_t,              C,   4*C);
  wconv_kernel<<<dim3(C/32,   4*C/32), tb, 0, stream>>>(Wmp, Wmp_t,              4*C, C);

  scale_rms_kernel<<<M, tb, 0, stream>>>(x, x0, lamR, lamX, scaled, pre);

  // fused QKV GEMM (N=3072, 768 blocks)
  gemm_qkv_kernel<<<dim3(3*C/128, M/128), tb, 0, stream>>>(pre, Wqkv_t, qb, kbuf, vtg);

  rope_rms_kernel<<<(M * H) / 4, tb, 0, stream>>>(qb,   cs, sn);
  rope_rms_kernel<<<(M * H) / 4, tb, 0, stream>>>(kbuf, cs, sn);

  attn_kernel<<<dim3(T/64, B * H), tb, 0, stream>>>(qb, kbuf, vtg, attnOut);

  // proj GEMM split-K=2 -> partials ; combine + rms
  gemm_kernel<4><<<dim3(C/128, M/128, 2), tb, 0, stream>>>(attnOut, Wp_t, projP, M, C, C);
  combine_rms_kernel<<<M, tb, 0, stream>>>(scaled, projP, projP + (size_t)M*C, scaled2, pre2);

  // fc GEMM + relu^2 (1024 blocks)
  gemm_kernel<1><<<dim3(4*C/128, M/128), tb, 0, stream>>>(pre2, Wfc_t, hbuf, M, 4*C, C);

  // mlp proj split-K=2 -> partials ; combine into out
  gemm_kernel<4><<<dim3(C/128, M/128, 2), tb, 0, stream>>>(hbuf, Wmp_t, mlpP0, M, C, 4*C);
  // note: partial z=0 -> mlpP0, z=1 -> mlpP0 + M*C  ... but we want z=1 in mlpP1:
  // gemm_kernel<4> writes out + z*M*N, so pass mlpP0 and ensure mlpP0+M*C == mlpP1.
  // mlpP0 is at 24MB, +16MB = 40MB (pre region). pre/attnOut is dead by now - OK.
  combine_out_kernel<<<(M*C)/1024, tb, 0, stream>>>(scaled2, mlpP0, mlpP0 + (size_t)M*C, out);
  (void)mlpP1;
}

// Round 4
// 422.453 us; speedup vs baseline: 1.3137x; 1.0853x over previous
//
#include <hip/hip_runtime.h>
#include <hip/hip_bf16.h>
#include <stdint.h>

typedef _Float16 f16;
typedef __attribute__((ext_vector_type(8))) _Float16 f16x8;
typedef __attribute__((ext_vector_type(4))) float f32x4;

__device__ __forceinline__ void g2l16(const void* g, void* l) {
  __builtin_amdgcn_global_load_lds(
      (const __attribute__((address_space(1))) uint32_t*)g,
      (__attribute__((address_space(3))) uint32_t*)l, 16, 0, 0);
}

// ---------------- weight transpose + fp32->f16 convert ----------------
// W: K x N (row-major fp32)  ->  Wt: N x K (row-major f16)
__global__ __launch_bounds__(256)
void wconv_kernel(const float* __restrict__ W, f16* __restrict__ Wt, int K, int N)
{
  __shared__ float tile[32][33];
  int n0 = blockIdx.x * 32, k0 = blockIdx.y * 32;
  int tx = threadIdx.x & 31, ty = threadIdx.x >> 5;  // ty 0..7
#pragma unroll
  for (int i = 0; i < 4; ++i)
    tile[ty + 8*i][tx] = W[(size_t)(k0 + ty + 8*i) * N + (n0 + tx)];
  __syncthreads();
#pragma unroll
  for (int i = 0; i < 4; ++i)
    Wt[(size_t)(n0 + ty + 8*i) * K + (k0 + tx)] = (f16)tile[tx][ty + 8*i];
}

// ---------------- scaled = x*lr + x0*lx ; pre = rmsnorm(scaled) ----------------
__global__ __launch_bounds__(256)
void scale_rms_kernel(const float* __restrict__ x, const float* __restrict__ x0,
                      const float* __restrict__ lamR, const float* __restrict__ lamX,
                      float* __restrict__ scaled, f16* __restrict__ pre)
{
  const int C = 1024;
  int row = blockIdx.x, tid = threadIdx.x;
  float lr = lamR[0], lx = lamX[0];
  size_t base = (size_t)row * C;
  float4 xv = ((const float4*)(x + base))[tid];
  float4 zv = ((const float4*)(x0 + base))[tid];
  float4 sv;
  sv.x = xv.x*lr + zv.x*lx;  sv.y = xv.y*lr + zv.y*lx;
  sv.z = xv.z*lr + zv.z*lx;  sv.w = xv.w*lr + zv.w*lx;
  float ss = sv.x*sv.x + sv.y*sv.y + sv.z*sv.z + sv.w*sv.w;
#pragma unroll
  for (int off = 32; off >= 1; off >>= 1) ss += __shfl_xor(ss, off);
  __shared__ float red[4];
  if ((tid & 63) == 0) red[tid >> 6] = ss;
  __syncthreads();
  float tot = red[0] + red[1] + red[2] + red[3];
  float rs = rsqrtf(tot * (1.0f / 1024.0f) + 1e-5f);
  ((float4*)(scaled + base))[tid] = sv;
  f16* p = pre + base + tid * 4;
  p[0] = (f16)(sv.x * rs); p[1] = (f16)(sv.y * rs);
  p[2] = (f16)(sv.z * rs); p[3] = (f16)(sv.w * rs);
}

// ---------------- combine_rms: scaled2 = resid+p0+p1 ; pre2 = rms(scaled2) f16 ----------------
__global__ __launch_bounds__(256)
void combine_rms_kernel(const float* __restrict__ resid, const float* __restrict__ p0,
                        const float* __restrict__ p1, float* __restrict__ scaled2,
                        f16* __restrict__ pre2)
{
  const int C = 1024;
  int row = blockIdx.x, tid = threadIdx.x;
  size_t base = (size_t)row * C;
  float4 rv = ((const float4*)(resid + base))[tid];
  float4 av = ((const float4*)(p0 + base))[tid];
  float4 bv = ((const float4*)(p1 + base))[tid];
  float4 sv;
  sv.x = rv.x + av.x + bv.x; sv.y = rv.y + av.y + bv.y;
  sv.z = rv.z + av.z + bv.z; sv.w = rv.w + av.w + bv.w;
  float ss = sv.x*sv.x + sv.y*sv.y + sv.z*sv.z + sv.w*sv.w;
#pragma unroll
  for (int off = 32; off >= 1; off >>= 1) ss += __shfl_xor(ss, off);
  __shared__ float red[4];
  if ((tid & 63) == 0) red[tid >> 6] = ss;
  __syncthreads();
  float tot = red[0] + red[1] + red[2] + red[3];
  float rs = rsqrtf(tot * (1.0f / 1024.0f) + 1e-5f);
  ((float4*)(scaled2 + base))[tid] = sv;
  f16* p = pre2 + base + tid * 4;
  p[0] = (f16)(sv.x * rs); p[1] = (f16)(sv.y * rs);
  p[2] = (f16)(sv.z * rs); p[3] = (f16)(sv.w * rs);
}

// ---------------- combine_out: out = resid + p0 + p1 ----------------
__global__ __launch_bounds__(256)
void combine_out_kernel(const float* __restrict__ resid, const float* __restrict__ p0,
                        const float* __restrict__ p1, float* __restrict__ out)
{
  size_t i = (size_t)blockIdx.x * 256 + threadIdx.x;
  float4 rv = ((const float4*)resid)[i];
  float4 av = ((const float4*)p0)[i];
  float4 bv = ((const float4*)p1)[i];
  float4 sv;
  sv.x = rv.x + av.x + bv.x; sv.y = rv.y + av.y + bv.y;
  sv.z = rv.z + av.z + bv.z; sv.w = rv.w + av.w + bv.w;
  ((float4*)out)[i] = sv;
}

// ---------------- in-place RoPE + rmsnorm on (B*T, H, 64) f16 ----------------
__global__ __launch_bounds__(256)
void rope_rms_kernel(f16* __restrict__ X, const float* __restrict__ cs,
                     const float* __restrict__ sn)
{
  int ridx = blockIdx.x * 4 + (threadIdx.x >> 6);  // over B*T*H
  int lane = threadIdx.x & 63;
  int h = ridx & 15;         // H = 16
  int bt = ridx >> 4;
  int t = bt & 2047;         // T = 2048
  size_t base = (size_t)bt * 1024 + h * 64;
  float xv = (float)X[base + lane];
  float other = __shfl_xor(xv, 32);
  float rot = (lane < 32) ? -other : other;   // concat([-x2, x1])
  float c = cs[t * 64 + lane], s = sn[t * 64 + lane];
  float y = xv * c + rot * s;
  float ss = y * y;
#pragma unroll
  for (int off = 32; off >= 1; off >>= 1) ss += __shfl_xor(ss, off);
  float r = rsqrtf(ss * (1.0f / 64.0f) + 1e-5f);
  X[base + lane] = (f16)(y * r);
}

// ---------------- GEMM: C[M,N] = A[M,K] @ Bt[N,K]^T, f16 in, fp32 acc ----------------
// EPI 1: f16 relu(v)^2 ; EPI 4: fp32 partial store at out + z*M*N (split-K via gridDim.z)
template<int EPI>
__global__ __launch_bounds__(256)
void gemm_kernel(const f16* __restrict__ A, const f16* __restrict__ Bt,
                 void* __restrict__ out, int M, int N, int K)
{
  __shared__ __align__(16) f16 As[128 * 32];
  __shared__ __align__(16) f16 Bs[128 * 32];
  const int tid = threadIdx.x;
  const int wave = tid >> 6, lane = tid & 63;
  const int col = lane & 15, quad = lane >> 4;
  const int m0 = blockIdx.y * 128, n0 = blockIdx.x * 128;
  const int wm = (wave >> 1) * 64, wn = (wave & 1) * 64;
  const int Ksub = K / gridDim.z;
  const int kBeg = blockIdx.z * Ksub, kEnd = kBeg + Ksub;
  f32x4 acc[4][4] = {};

  const size_t rowb = (size_t)K * 2;
  const char* Agp = (const char*)A  + (size_t)m0 * rowb;
  const char* Bgp = (const char*)Bt + (size_t)n0 * rowb;

  for (int k0 = kBeg; k0 < kEnd; k0 += 32) {
#pragma unroll
    for (int i = 0; i < 2; ++i) {
      int e = i * 256 + tid;
      int r = e >> 2;
      int cb = (e & 3) << 4;
      int lbase = (i * 256 + wave * 64) << 4;   // wave-uniform; HW adds lane*16
      g2l16(Agp + (size_t)r * rowb + (size_t)k0 * 2 + cb, (char*)As + lbase);
      g2l16(Bgp + (size_t)r * rowb + (size_t)k0 * 2 + cb, (char*)Bs + lbase);
    }
    __syncthreads();
    f16x8 af[4], bf[4];
#pragma unroll
    for (int t = 0; t < 4; ++t)
      af[t] = *(const f16x8*)(As + (wm + t*16 + col) * 32 + quad * 8);
#pragma unroll
    for (int t = 0; t < 4; ++t)
      bf[t] = *(const f16x8*)(Bs + (wn + t*16 + col) * 32 + quad * 8);
#pragma unroll
    for (int mt = 0; mt < 4; ++mt)
#pragma unroll
      for (int nt = 0; nt < 4; ++nt)
        acc[mt][nt] = __builtin_amdgcn_mfma_f32_16x16x32_f16(af[mt], bf[nt], acc[mt][nt], 0, 0, 0);
    __syncthreads();
  }
  float* outz = (EPI == 4) ? ((float*)out + (size_t)blockIdx.z * M * N) : nullptr;
#pragma unroll
  for (int mt = 0; mt < 4; ++mt) {
#pragma unroll
    for (int nt = 0; nt < 4; ++nt) {
#pragma unroll
      for (int r = 0; r < 4; ++r) {
        int row = m0 + wm + mt * 16 + quad * 4 + r;   // C/D: row = quad*4+reg
        int cc  = n0 + wn + nt * 16 + col;            //      col = lane&15
        size_t idx = (size_t)row * N + cc;
        float v = acc[mt][nt][r];
        if (EPI == 1) {
          float tv = v > 0.0f ? v : 0.0f;
          ((f16*)out)[idx] = (f16)(tv * tv);
        } else {
          outz[idx] = v;
        }
      }
    }
  }
}

// ---------------- fused QKV GEMM: A[4096,1024] @ Wqkv[3072,1024]^T ----------------
// cols 0..1023 -> qb, 1024..2047 -> kbuf (both [b,t,h,d] f16),
// cols 2048..3071 -> vtg transposed: [(b*16+h)*64+d][t]
__global__ __launch_bounds__(256)
void gemm_qkv_kernel(const f16* __restrict__ A, const f16* __restrict__ Bt,
                     f16* __restrict__ qb, f16* __restrict__ kbuf, f16* __restrict__ vtg)
{
  const int N = 3072, K = 1024;
  __shared__ __align__(16) f16 As[128 * 32];
  __shared__ __align__(16) f16 Bs[128 * 32];
  const int tid = threadIdx.x;
  const int wave = tid >> 6, lane = tid & 63;
  const int col = lane & 15, quad = lane >> 4;
  const int m0 = blockIdx.y * 128, n0 = blockIdx.x * 128;
  const int wm = (wave >> 1) * 64, wn = (wave & 1) * 64;
  f32x4 acc[4][4] = {};

  const size_t rowb = (size_t)K * 2;
  const char* Agp = (const char*)A  + (size_t)m0 * rowb;
  const char* Bgp = (const char*)Bt + (size_t)n0 * rowb;

  for (int k0 = 0; k0 < K; k0 += 32) {
#pragma unroll
    for (int i = 0; i < 2; ++i) {
      int e = i * 256 + tid;
      int r = e >> 2;
      int cb = (e & 3) << 4;
      int lbase = (i * 256 + wave * 64) << 4;
      g2l16(Agp + (size_t)r * rowb + (size_t)k0 * 2 + cb, (char*)As + lbase);
      g2l16(Bgp + (size_t)r * rowb + (size_t)k0 * 2 + cb, (char*)Bs + lbase);
    }
    __syncthreads();
    f16x8 af[4], bf[4];
#pragma unroll
    for (int t = 0; t < 4; ++t)
      af[t] = *(const f16x8*)(As + (wm + t*16 + col) * 32 + quad * 8);
#pragma unroll
    for (int t = 0; t < 4; ++t)
      bf[t] = *(const f16x8*)(Bs + (wn + t*16 + col) * 32 + quad * 8);
#pragma unroll
    for (int mt = 0; mt < 4; ++mt)
#pragma unroll
      for (int nt = 0; nt < 4; ++nt)
        acc[mt][nt] = __builtin_amdgcn_mfma_f32_16x16x32_f16(af[mt], bf[nt], acc[mt][nt], 0, 0, 0);
    __syncthreads();
  }
  const int sel = (n0 + wn) >> 10;   // 0: Q, 1: K, 2: V (wave-uniform)
#pragma unroll
  for (int mt = 0; mt < 4; ++mt) {
#pragma unroll
    for (int nt = 0; nt < 4; ++nt) {
#pragma unroll
      for (int r = 0; r < 4; ++r) {
        int row = m0 + wm + mt * 16 + quad * 4 + r;
        int cc  = n0 + wn + nt * 16 + col;
        float v = acc[mt][nt][r];
        if (sel == 0) {
          qb[(size_t)row * 1024 + (cc & 1023)] = (f16)v;
        } else if (sel == 1) {
          kbuf[(size_t)row * 1024 + (cc & 1023)] = (f16)v;
        } else {
          int b = row >> 11, t = row & 2047;
          int hh = (cc - 2048) >> 6, dd = cc & 63;
          vtg[((size_t)((b * 16 + hh) * 64 + dd)) * 2048 + t] = (f16)v;
        }
      }
    }
  }
}

// ---------------- causal flash attention, hd=64, no-max softmax, dbuf staging ----------------
// After rmsnorm ||q||=||k||=8 exactly -> |score| <= 8 -> exp(score) <= e^8 < f16 max.
// p = exp(score) directly; no running max/rescale; l summed per-lane, reduced at end.
// Q,K: [b,t,h,d] f16 ; Vt: [(b*16+h)*64+d][t] f16 ; O: [b,t,h,d] f16
// grid (bh, qt): bh fastest => all q-tiles of one head land on XCD bh%8 (L2 locality).
// K/V staging double-buffered: g2l for tile kt+1 issued right after the barrier that
// publishes tile kt; next barrier's vmcnt drain finds them complete.
__global__ __launch_bounds__(256)
void attn_kernel(const f16* __restrict__ Q, const f16* __restrict__ Kc,
                 const f16* __restrict__ Vt, f16* __restrict__ O)
{
  const int T = 2048, C = 1024;
  __shared__ __align__(16) f16 Ks[2][64 * 64];
  __shared__ __align__(16) f16 Vs[2][64 * 64];
  __shared__ __align__(16) f16 Ps[4][16 * 64];
  const int tid = threadIdx.x, wave = tid >> 6, lane = tid & 63;
  const int col = lane & 15, quad = lane >> 4;
  const int bh = blockIdx.x, b = bh >> 4, h = bh & 15;
  const int qt = (int)gridDim.y - 1 - (int)blockIdx.y;  // heavy q-tiles first
  const int q0 = qt * 64;

  const f16* qb = Q  + ((size_t)b * T) * C + h * 64;
  const f16* kb = Kc + ((size_t)b * T) * C + h * 64;
  const f16* vb = Vt + ((size_t)bh * 64) * T;

  // Q fragments (A-operand): row = q0 + wave*16 + col
  f16x8 aq[2];
#pragma unroll
  for (int ks = 0; ks < 2; ++ks)
    aq[ks] = *(const f16x8*)(qb + (size_t)(q0 + wave*16 + col) * C + ks*32 + quad*8);

  f32x4 o_acc[4];
#pragma unroll
  for (int dt = 0; dt < 4; ++dt) o_acc[dt] = (f32x4){0.f,0.f,0.f,0.f};
  float l_part[4] = {0.f, 0.f, 0.f, 0.f};

  const int srow = lane >> 3;                 // row within 8-row staging chunk
  const int sblk = (lane & 7) ^ srow;         // permuted 16B-block index

  // stage tile 0 into buffer 0
#pragma unroll
  for (int i = 0; i < 2; ++i) {
    int r0 = wave * 16 + 8 * i;
    g2l16(kb + (size_t)(r0 + srow) * C + sblk * 8, (char*)Ks[0] + r0 * 128);
    g2l16(vb + (size_t)(r0 + srow) * T + sblk * 8, (char*)Vs[0] + r0 * 128);
  }

  int cur = 0;
  for (int kt = 0; kt <= qt; ++kt) {
    __syncthreads();   // drains vmcnt: buf[cur] staged; all waves done reading buf[cur^1]

    if (kt < qt) {     // prefetch next tile into the other buffer
      const int ks1 = (kt + 1) * 64;
#pragma unroll
      for (int i = 0; i < 2; ++i) {
        int r0 = wave * 16 + 8 * i;
        g2l16(kb + (size_t)(ks1 + r0 + srow) * C + sblk * 8, (char*)Ks[cur ^ 1] + r0 * 128);
        g2l16(vb + (size_t)(r0 + srow) * T + ks1 + sblk * 8, (char*)Vs[cur ^ 1] + r0 * 128);
      }
    }

    // S = Q K^T
    f32x4 s[4];
#pragma unroll
    for (int nt = 0; nt < 4; ++nt) s[nt] = (f32x4){0.f,0.f,0.f,0.f};
#pragma unroll
    for (int ks = 0; ks < 2; ++ks) {
#pragma unroll
      for (int nt = 0; nt < 4; ++nt) {
        int key = nt * 16 + col;
        f16x8 bk = *(const f16x8*)(Ks[cur] + key * 64 + (((ks*4 + quad) ^ (key & 7)) * 8));
        s[nt] = __builtin_amdgcn_mfma_f32_16x16x32_f16(aq[ks], bk, s[nt], 0, 0, 0);
      }
    }

    const bool masked = (kt == qt);
#pragma unroll
    for (int r = 0; r < 4; ++r) {
      const int qloc = quad * 4 + r;          // row within wave's 16-row tile
      float p[4];
#pragma unroll
      for (int nt = 0; nt < 4; ++nt) {
        float pv = __expf(s[nt][r] * 0.125f);
        if (masked && (nt * 16 + col > wave * 16 + qloc)) pv = 0.0f;
        p[nt] = pv;
      }
      l_part[r] += (p[0] + p[1]) + (p[2] + p[3]);
#pragma unroll
      for (int nt = 0; nt < 4; ++nt) {
        int kblk = nt * 2 + (col >> 3);
        Ps[wave][qloc * 64 + ((kblk ^ (qloc & 7)) * 8) + (col & 7)] = (f16)p[nt];
      }
    }

    // O += P V   (Ps is per-wave; same-wave DS ordering guarantees visibility)
#pragma unroll
    for (int ks = 0; ks < 2; ++ks) {
      f16x8 ap = *(const f16x8*)(&Ps[wave][0] + col * 64 + (((ks*4 + quad) ^ (col & 7)) * 8));
#pragma unroll
      for (int dt = 0; dt < 4; ++dt) {
        int d = dt * 16 + col;
        f16x8 bv = *(const f16x8*)(Vs[cur] + d * 64 + (((ks*4 + quad) ^ (d & 7)) * 8));
        o_acc[dt] = __builtin_amdgcn_mfma_f32_16x16x32_f16(ap, bv, o_acc[dt], 0, 0, 0);
      }
    }
    cur ^= 1;
  }

  // final row-sum reduction (16 lanes per row)
#pragma unroll
  for (int r = 0; r < 4; ++r) {
#pragma unroll
    for (int off = 8; off >= 1; off >>= 1)
      l_part[r] += __shfl_xor(l_part[r], off, 16);
  }
#pragma unroll
  for (int dt = 0; dt < 4; ++dt) {
#pragma unroll
    for (int r = 0; r < 4; ++r) {
      int qr = q0 + wave * 16 + quad * 4 + r;
      float v = o_acc[dt][r] / l_part[r];
      O[((size_t)b * T + qr) * C + h * 64 + dt * 16 + col] = (f16)v;
    }
  }
}

// ---------------- orchestration ----------------
extern "C" void kernel_launch(void* const* d_in, const int* in_sizes, int n_in,
                              void* d_out, int out_size, void* d_ws, size_t ws_size,
                              hipStream_t stream)
{
  const float* x    = (const float*)d_in[0];
  const float* x0   = (const float*)d_in[1];
  const float* lamR = (const float*)d_in[2];
  const float* lamX = (const float*)d_in[3];
  const float* cs   = (const float*)d_in[4];
  const float* sn   = (const float*)d_in[5];
  const float* Wq   = (const float*)d_in[6];
  const float* Wk   = (const float*)d_in[7];
  const float* Wv   = (const float*)d_in[8];
  const float* Wp   = (const float*)d_in[9];
  const float* Wfc  = (const float*)d_in[10];
  const float* Wmp  = (const float*)d_in[11];
  float* out = (float*)d_out;

  const int B = 2, T = 2048, C = 1024, H = 16;
  const int M = B * T;  // 4096
  const size_t MB = 1ull << 20;
  char* ws = (char*)d_ws;
  f16*   Wqkv_t = (f16*)(ws + 0 * MB);     // 6 MB: Wq|Wk|Wv each [1024][1024] f16
  f16*   Wp_t   = (f16*)(ws + 6 * MB);     // 2 MB
  f16*   Wfc_t  = (f16*)(ws + 8 * MB);     // 8 MB  (4096 x 1024)
  f16*   Wmp_t  = (f16*)(ws + 16 * MB);    // 8 MB  (1024 x 4096)
  float* scaled  = (float*)(ws + 24 * MB); // 16 MB fp32   [reused: mlp partial 0]
  f16*   pre     = (f16*)(ws + 40 * MB);   // 8 MB         [reused: attnOut, mlp partial 1]
  f16*   qb      = (f16*)(ws + 48 * MB);   // 8 MB         [reused: pre2]
  f16*   kbuf    = (f16*)(ws + 56 * MB);   // 8 MB
  f16*   vtg     = (f16*)(ws + 64 * MB);   // 8 MB V^T
  float* scaled2 = (float*)(ws + 72 * MB); // 16 MB fp32
  f16*   hbuf    = (f16*)(ws + 88 * MB);   // 32 MB (4096x4096 f16) [first: proj partials]
  f16*   attnOut = pre;
  f16*   pre2    = qb;
  float* projP   = (float*)(ws + 88 * MB); // 2 x 16 MB fp32 (before hbuf is written)
  float* mlpP0   = (float*)(ws + 24 * MB); // scaled region (free after combine_rms);
                                           // z=1 partial lands at +16MB = pre region (dead)

  dim3 tb(256);
  // weight convert+transpose (K x N fp32 -> N x K f16)
  wconv_kernel<<<dim3(C/32,   C/32),   tb, 0, stream>>>(Wq,  Wqkv_t,             C,   C);
  wconv_kernel<<<dim3(C/32,   C/32),   tb, 0, stream>>>(Wk,  Wqkv_t + 1024*1024, C,   C);
  wconv_kernel<<<dim3(C/32,   C/32),   tb, 0, stream>>>(Wv,  Wqkv_t + 2048*1024, C,   C);
  wconv_kernel<<<dim3(C/32,   C/32),   tb, 0, stream>>>(Wp,  Wp_t,               C,   C);
  wconv_kernel<<<dim3(4*C/32, C/32),   tb, 0, stream>>>(Wfc, Wfc_t,              C,   4*C);
  wconv_kernel<<<dim3(C/32,   4*C/32), tb, 0, stream>>>(Wmp, Wmp_t,              4*C, C);

  scale_rms_kernel<<<M, tb, 0, stream>>>(x, x0, lamR, lamX, scaled, pre);

  // fused QKV GEMM (N=3072, 768 blocks)
  gemm_qkv_kernel<<<dim3(3*C/128, M/128), tb, 0, stream>>>(pre, Wqkv_t, qb, kbuf, vtg);

  rope_rms_kernel<<<(M * H) / 4, tb, 0, stream>>>(qb,   cs, sn);
  rope_rms_kernel<<<(M * H) / 4, tb, 0, stream>>>(kbuf, cs, sn);

  // grid (bh, qt): bh fastest -> per-head XCD pinning
  attn_kernel<<<dim3(B * H, T/64), tb, 0, stream>>>(qb, kbuf, vtg, attnOut);

  // proj GEMM split-K=2 -> partials ; combine + rms
  gemm_kernel<4><<<dim3(C/128, M/128, 2), tb, 0, stream>>>(attnOut, Wp_t, projP, M, C, C);
  combine_rms_kernel<<<M, tb, 0, stream>>>(scaled, projP, projP + (size_t)M*C, scaled2, pre2);

  // fc GEMM + relu^2 (1024 blocks)
  gemm_kernel<1><<<dim3(4*C/128, M/128), tb, 0, stream>>>(pre2, Wfc_t, hbuf, M, 4*C, C);

  // mlp proj split-K=2 -> partials ; combine into out
  gemm_kernel<4><<<dim3(C/128, M/128, 2), tb, 0, stream>>>(hbuf, Wmp_t, mlpP0, M, C, 4*C);
  combine_out_kernel<<<(M*C)/1024, tb, 0, stream>>>(scaled2, mlpP0, mlpP0 + (size_t)M*C, out);
}

// Round 5
// 419.355 us; speedup vs baseline: 1.3234x; 1.0074x over previous
//
#include <hip/hip_runtime.h>
#include <hip/hip_bf16.h>
#include <stdint.h>

typedef _Float16 f16;
typedef __attribute__((ext_vector_type(8))) _Float16 f16x8;
typedef __attribute__((ext_vector_type(4))) _Float16 f16x4;
typedef __attribute__((ext_vector_type(4))) float f32x4;

__device__ __forceinline__ void g2l16(const void* g, void* l) {
  __builtin_amdgcn_global_load_lds(
      (const __attribute__((address_space(1))) uint32_t*)g,
      (__attribute__((address_space(3))) uint32_t*)l, 16, 0, 0);
}

// ---------------- weight transpose + fp32->f16 convert ----------------
__global__ __launch_bounds__(256)
void wconv_kernel(const float* __restrict__ W, f16* __restrict__ Wt, int K, int N)
{
  __shared__ float tile[32][33];
  int n0 = blockIdx.x * 32, k0 = blockIdx.y * 32;
  int tx = threadIdx.x & 31, ty = threadIdx.x >> 5;
#pragma unroll
  for (int i = 0; i < 4; ++i)
    tile[ty + 8*i][tx] = W[(size_t)(k0 + ty + 8*i) * N + (n0 + tx)];
  __syncthreads();
#pragma unroll
  for (int i = 0; i < 4; ++i)
    Wt[(size_t)(n0 + ty + 8*i) * K + (k0 + tx)] = (f16)tile[tx][ty + 8*i];
}

// ---------------- scaled = x*lr + x0*lx ; pre = rmsnorm(scaled) ----------------
__global__ __launch_bounds__(256)
void scale_rms_kernel(const float* __restrict__ x, const float* __restrict__ x0,
                      const float* __restrict__ lamR, const float* __restrict__ lamX,
                      float* __restrict__ scaled, f16* __restrict__ pre)
{
  const int C = 1024;
  int row = blockIdx.x, tid = threadIdx.x;
  float lr = lamR[0], lx = lamX[0];
  size_t base = (size_t)row * C;
  float4 xv = ((const float4*)(x + base))[tid];
  float4 zv = ((const float4*)(x0 + base))[tid];
  float4 sv;
  sv.x = xv.x*lr + zv.x*lx;  sv.y = xv.y*lr + zv.y*lx;
  sv.z = xv.z*lr + zv.z*lx;  sv.w = xv.w*lr + zv.w*lx;
  float ss = sv.x*sv.x + sv.y*sv.y + sv.z*sv.z + sv.w*sv.w;
#pragma unroll
  for (int off = 32; off >= 1; off >>= 1) ss += __shfl_xor(ss, off);
  __shared__ float red[4];
  if ((tid & 63) == 0) red[tid >> 6] = ss;
  __syncthreads();
  float tot = red[0] + red[1] + red[2] + red[3];
  float rs = rsqrtf(tot * (1.0f / 1024.0f) + 1e-5f);
  ((float4*)(scaled + base))[tid] = sv;
  f16* p = pre + base + tid * 4;
  p[0] = (f16)(sv.x * rs); p[1] = (f16)(sv.y * rs);
  p[2] = (f16)(sv.z * rs); p[3] = (f16)(sv.w * rs);
}

// ---------------- combine_rms: scaled2 = resid+p0+p1 (f16 partials) ; pre2 = rms ----------------
__global__ __launch_bounds__(256)
void combine_rms_kernel(const float* __restrict__ resid, const f16* __restrict__ p0,
                        const f16* __restrict__ p1, float* __restrict__ scaled2,
                        f16* __restrict__ pre2)
{
  const int C = 1024;
  int row = blockIdx.x, tid = threadIdx.x;
  size_t base = (size_t)row * C;
  float4 rv = ((const float4*)(resid + base))[tid];
  f16x4 av = ((const f16x4*)(p0 + base))[tid];
  f16x4 bv = ((const f16x4*)(p1 + base))[tid];
  float4 sv;
  sv.x = rv.x + (float)av[0] + (float)bv[0];
  sv.y = rv.y + (float)av[1] + (float)bv[1];
  sv.z = rv.z + (float)av[2] + (float)bv[2];
  sv.w = rv.w + (float)av[3] + (float)bv[3];
  float ss = sv.x*sv.x + sv.y*sv.y + sv.z*sv.z + sv.w*sv.w;
#pragma unroll
  for (int off = 32; off >= 1; off >>= 1) ss += __shfl_xor(ss, off);
  __shared__ float red[4];
  if ((tid & 63) == 0) red[tid >> 6] = ss;
  __syncthreads();
  float tot = red[0] + red[1] + red[2] + red[3];
  float rs = rsqrtf(tot * (1.0f / 1024.0f) + 1e-5f);
  ((float4*)(scaled2 + base))[tid] = sv;
  f16* p = pre2 + base + tid * 4;
  p[0] = (f16)(sv.x * rs); p[1] = (f16)(sv.y * rs);
  p[2] = (f16)(sv.z * rs); p[3] = (f16)(sv.w * rs);
}

// ---------------- combine_out: out = resid + p0 + p1 (f16 partials) ----------------
__global__ __launch_bounds__(256)
void combine_out_kernel(const float* __restrict__ resid, const f16* __restrict__ p0,
                        const f16* __restrict__ p1, float* __restrict__ out)
{
  size_t i = (size_t)blockIdx.x * 256 + threadIdx.x;
  float4 rv = ((const float4*)resid)[i];
  f16x4 av = ((const f16x4*)p0)[i];
  f16x4 bv = ((const f16x4*)p1)[i];
  float4 sv;
  sv.x = rv.x + (float)av[0] + (float)bv[0];
  sv.y = rv.y + (float)av[1] + (float)bv[1];
  sv.z = rv.z + (float)av[2] + (float)bv[2];
  sv.w = rv.w + (float)av[3] + (float)bv[3];
  ((float4*)out)[i] = sv;
}

// ---------------- in-place RoPE + rmsnorm on (B*T, H, 64) f16 ----------------
__global__ __launch_bounds__(256)
void rope_rms_kernel(f16* __restrict__ X, const float* __restrict__ cs,
                     const float* __restrict__ sn)
{
  int ridx = blockIdx.x * 4 + (threadIdx.x >> 6);
  int lane = threadIdx.x & 63;
  int h = ridx & 15;
  int bt = ridx >> 4;
  int t = bt & 2047;
  size_t base = (size_t)bt * 1024 + h * 64;
  float xv = (float)X[base + lane];
  float other = __shfl_xor(xv, 32);
  float rot = (lane < 32) ? -other : other;
  float c = cs[t * 64 + lane], s = sn[t * 64 + lane];
  float y = xv * c + rot * s;
  float ss = y * y;
#pragma unroll
  for (int off = 32; off >= 1; off >>= 1) ss += __shfl_xor(ss, off);
  float r = rsqrtf(ss * (1.0f / 64.0f) + 1e-5f);
  X[base + lane] = (f16)(y * r);
}

// ---------------- GEMM: C[M,N] = A[M,K] @ Bt[N,K]^T, f16 in, fp32 acc ----------------
// XCD-aware 1-D grid: id&7 = XCD; within an XCD, n iterates fastest so all n-blocks
// sharing one A-panel hit the same L2; z grouped so the W half stays resident.
// EPI 1: f16 relu(v)^2 ; EPI 4: f16 partial at out + z*M*N (split-K)
template<int EPI>
__global__ __launch_bounds__(256)
void gemm_kernel(const f16* __restrict__ A, const f16* __restrict__ Bt,
                 void* __restrict__ out, int M, int N, int K, int nb, int zb)
{
  __shared__ __align__(16) f16 As[128 * 32];
  __shared__ __align__(16) f16 Bs[128 * 32];
  const int tid = threadIdx.x;
  const int wave = tid >> 6, lane = tid & 63;
  const int col = lane & 15, quad = lane >> 4;
  // swizzled decode
  const int id = blockIdx.x;
  const int xcd = id & 7, s = id >> 3;
  const int n_i = s % nb;
  const int p = s / nb;
  const int mpx = (M >> 7) >> 3;        // m-panels per XCD per z
  const int zz = p / mpx;
  const int m_i = xcd * mpx + (p % mpx);
  const int m0 = m_i * 128, n0 = n_i * 128;
  const int wm = (wave >> 1) * 64, wn = (wave & 1) * 64;
  const int Ksub = K / zb;
  const int kBeg = zz * Ksub, kEnd = kBeg + Ksub;
  f32x4 acc[4][4] = {};

  const size_t rowb = (size_t)K * 2;
  const char* Agp = (const char*)A  + (size_t)m0 * rowb;
  const char* Bgp = (const char*)Bt + (size_t)n0 * rowb;

  for (int k0 = kBeg; k0 < kEnd; k0 += 32) {
#pragma unroll
    for (int i = 0; i < 2; ++i) {
      int e = i * 256 + tid;
      int r = e >> 2;
      int cb = (e & 3) << 4;
      int lbase = (i * 256 + wave * 64) << 4;   // wave-uniform; HW adds lane*16
      g2l16(Agp + (size_t)r * rowb + (size_t)k0 * 2 + cb, (char*)As + lbase);
      g2l16(Bgp + (size_t)r * rowb + (size_t)k0 * 2 + cb, (char*)Bs + lbase);
    }
    __syncthreads();
    f16x8 af[4], bf[4];
#pragma unroll
    for (int t = 0; t < 4; ++t)
      af[t] = *(const f16x8*)(As + (wm + t*16 + col) * 32 + quad * 8);
#pragma unroll
    for (int t = 0; t < 4; ++t)
      bf[t] = *(const f16x8*)(Bs + (wn + t*16 + col) * 32 + quad * 8);
#pragma unroll
    for (int mt = 0; mt < 4; ++mt)
#pragma unroll
      for (int nt = 0; nt < 4; ++nt)
        acc[mt][nt] = __builtin_amdgcn_mfma_f32_16x16x32_f16(af[mt], bf[nt], acc[mt][nt], 0, 0, 0);
    __syncthreads();
  }
  f16* outz = (EPI == 4) ? ((f16*)out + (size_t)zz * M * N) : (f16*)out;
#pragma unroll
  for (int mt = 0; mt < 4; ++mt) {
#pragma unroll
    for (int nt = 0; nt < 4; ++nt) {
#pragma unroll
      for (int r = 0; r < 4; ++r) {
        int row = m0 + wm + mt * 16 + quad * 4 + r;
        int cc  = n0 + wn + nt * 16 + col;
        size_t idx = (size_t)row * N + cc;
        float v = acc[mt][nt][r];
        if (EPI == 1) {
          float tv = v > 0.0f ? v : 0.0f;
          outz[idx] = (f16)(tv * tv);
        } else {
          outz[idx] = (f16)v;
        }
      }
    }
  }
}

// ---------------- fused QKV GEMM: A[4096,1024] @ Wqkv[3072,1024]^T ----------------
__global__ __launch_bounds__(256)
void gemm_qkv_kernel(const f16* __restrict__ A, const f16* __restrict__ Bt,
                     f16* __restrict__ qb, f16* __restrict__ kbuf, f16* __restrict__ vtg)
{
  const int N = 3072, K = 1024, nb = 24;
  __shared__ __align__(16) f16 As[128 * 32];
  __shared__ __align__(16) f16 Bs[128 * 32];
  const int tid = threadIdx.x;
  const int wave = tid >> 6, lane = tid & 63;
  const int col = lane & 15, quad = lane >> 4;
  const int id = blockIdx.x;
  const int xcd = id & 7, s = id >> 3;
  const int n_i = s % nb;
  const int m_i = xcd * 4 + (s / nb);     // mpx = 32/8 = 4
  const int m0 = m_i * 128, n0 = n_i * 128;
  const int wm = (wave >> 1) * 64, wn = (wave & 1) * 64;
  f32x4 acc[4][4] = {};

  const size_t rowb = (size_t)K * 2;
  const char* Agp = (const char*)A  + (size_t)m0 * rowb;
  const char* Bgp = (const char*)Bt + (size_t)n0 * rowb;

  for (int k0 = 0; k0 < K; k0 += 32) {
#pragma unroll
    for (int i = 0; i < 2; ++i) {
      int e = i * 256 + tid;
      int r = e >> 2;
      int cb = (e & 3) << 4;
      int lbase = (i * 256 + wave * 64) << 4;
      g2l16(Agp + (size_t)r * rowb + (size_t)k0 * 2 + cb, (char*)As + lbase);
      g2l16(Bgp + (size_t)r * rowb + (size_t)k0 * 2 + cb, (char*)Bs + lbase);
    }
    __syncthreads();
    f16x8 af[4], bf[4];
#pragma unroll
    for (int t = 0; t < 4; ++t)
      af[t] = *(const f16x8*)(As + (wm + t*16 + col) * 32 + quad * 8);
#pragma unroll
    for (int t = 0; t < 4; ++t)
      bf[t] = *(const f16x8*)(Bs + (wn + t*16 + col) * 32 + quad * 8);
#pragma unroll
    for (int mt = 0; mt < 4; ++mt)
#pragma unroll
      for (int nt = 0; nt < 4; ++nt)
        acc[mt][nt] = __builtin_amdgcn_mfma_f32_16x16x32_f16(af[mt], bf[nt], acc[mt][nt], 0, 0, 0);
    __syncthreads();
  }
  const int sel = (n0 + wn) >> 10;   // 0: Q, 1: K, 2: V (wave-uniform)
#pragma unroll
  for (int mt = 0; mt < 4; ++mt) {
#pragma unroll
    for (int nt = 0; nt < 4; ++nt) {
#pragma unroll
      for (int r = 0; r < 4; ++r) {
        int row = m0 + wm + mt * 16 + quad * 4 + r;
        int cc  = n0 + wn + nt * 16 + col;
        float v = acc[mt][nt][r];
        if (sel == 0) {
          qb[(size_t)row * 1024 + (cc & 1023)] = (f16)v;
        } else if (sel == 1) {
          kbuf[(size_t)row * 1024 + (cc & 1023)] = (f16)v;
        } else {
          int b = row >> 11, t = row & 2047;
          int hh = (cc - 2048) >> 6, dd = cc & 63;
          vtg[((size_t)((b * 16 + hh) * 64 + dd)) * 2048 + t] = (f16)v;
        }
      }
    }
  }
}

// ---------------- causal flash attention, hd=64, no-max softmax, dbuf staging ----------------
__global__ __launch_bounds__(256)
void attn_kernel(const f16* __restrict__ Q, const f16* __restrict__ Kc,
                 const f16* __restrict__ Vt, f16* __restrict__ O)
{
  const int T = 2048, C = 1024;
  __shared__ __align__(16) f16 Ks[2][64 * 64];
  __shared__ __align__(16) f16 Vs[2][64 * 64];
  __shared__ __align__(16) f16 Ps[4][16 * 64];
  const int tid = threadIdx.x, wave = tid >> 6, lane = tid & 63;
  const int col = lane & 15, quad = lane >> 4;
  const int bh = blockIdx.x, b = bh >> 4, h = bh & 15;
  const int qt = (int)gridDim.y - 1 - (int)blockIdx.y;  // heavy q-tiles first
  const int q0 = qt * 64;

  const f16* qb = Q  + ((size_t)b * T) * C + h * 64;
  const f16* kb = Kc + ((size_t)b * T) * C + h * 64;
  const f16* vb = Vt + ((size_t)bh * 64) * T;

  f16x8 aq[2];
#pragma unroll
  for (int ks = 0; ks < 2; ++ks)
    aq[ks] = *(const f16x8*)(qb + (size_t)(q0 + wave*16 + col) * C + ks*32 + quad*8);

  f32x4 o_acc[4];
#pragma unroll
  for (int dt = 0; dt < 4; ++dt) o_acc[dt] = (f32x4){0.f,0.f,0.f,0.f};
  float l_part[4] = {0.f, 0.f, 0.f, 0.f};

  const int srow = lane >> 3;
  const int sblk = (lane & 7) ^ srow;

#pragma unroll
  for (int i = 0; i < 2; ++i) {
    int r0 = wave * 16 + 8 * i;
    g2l16(kb + (size_t)(r0 + srow) * C + sblk * 8, (char*)Ks[0] + r0 * 128);
    g2l16(vb + (size_t)(r0 + srow) * T + sblk * 8, (char*)Vs[0] + r0 * 128);
  }

  int cur = 0;
  for (int kt = 0; kt <= qt; ++kt) {
    __syncthreads();

    if (kt < qt) {
      const int ks1 = (kt + 1) * 64;
#pragma unroll
      for (int i = 0; i < 2; ++i) {
        int r0 = wave * 16 + 8 * i;
        g2l16(kb + (size_t)(ks1 + r0 + srow) * C + sblk * 8, (char*)Ks[cur ^ 1] + r0 * 128);
        g2l16(vb + (size_t)(r0 + srow) * T + ks1 + sblk * 8, (char*)Vs[cur ^ 1] + r0 * 128);
      }
    }

    f32x4 s[4];
#pragma unroll
    for (int nt = 0; nt < 4; ++nt) s[nt] = (f32x4){0.f,0.f,0.f,0.f};
#pragma unroll
    for (int ks = 0; ks < 2; ++ks) {
#pragma unroll
      for (int nt = 0; nt < 4; ++nt) {
        int key = nt * 16 + col;
        f16x8 bk = *(const f16x8*)(Ks[cur] + key * 64 + (((ks*4 + quad) ^ (key & 7)) * 8));
        s[nt] = __builtin_amdgcn_mfma_f32_16x16x32_f16(aq[ks], bk, s[nt], 0, 0, 0);
      }
    }

    const bool masked = (kt == qt);
#pragma unroll
    for (int r = 0; r < 4; ++r) {
      const int qloc = quad * 4 + r;
      float p[4];
#pragma unroll
      for (int nt = 0; nt < 4; ++nt) {
        float pv = __expf(s[nt][r] * 0.125f);
        if (masked && (nt * 16 + col > wave * 16 + qloc)) pv = 0.0f;
        p[nt] = pv;
      }
      l_part[r] += (p[0] + p[1]) + (p[2] + p[3]);
#pragma unroll
      for (int nt = 0; nt < 4; ++nt) {
        int kblk = nt * 2 + (col >> 3);
        Ps[wave][qloc * 64 + ((kblk ^ (qloc & 7)) * 8) + (col & 7)] = (f16)p[nt];
      }
    }

#pragma unroll
    for (int ks = 0; ks < 2; ++ks) {
      f16x8 ap = *(const f16x8*)(&Ps[wave][0] + col * 64 + (((ks*4 + quad) ^ (col & 7)) * 8));
#pragma unroll
      for (int dt = 0; dt < 4; ++dt) {
        int d = dt * 16 + col;
        f16x8 bv = *(const f16x8*)(Vs[cur] + d * 64 + (((ks*4 + quad) ^ (d & 7)) * 8));
        o_acc[dt] = __builtin_amdgcn_mfma_f32_16x16x32_f16(ap, bv, o_acc[dt], 0, 0, 0);
      }
    }
    cur ^= 1;
  }

#pragma unroll
  for (int r = 0; r < 4; ++r) {
#pragma unroll
    for (int off = 8; off >= 1; off >>= 1)
      l_part[r] += __shfl_xor(l_part[r], off, 16);
  }
#pragma unroll
  for (int dt = 0; dt < 4; ++dt) {
#pragma unroll
    for (int r = 0; r < 4; ++r) {
      int qr = q0 + wave * 16 + quad * 4 + r;
      float v = o_acc[dt][r] / l_part[r];
      O[((size_t)b * T + qr) * C + h * 64 + dt * 16 + col] = (f16)v;
    }
  }
}

// ---------------- orchestration ----------------
extern "C" void kernel_launch(void* const* d_in, const int* in_sizes, int n_in,
                              void* d_out, int out_size, void* d_ws, size_t ws_size,
                              hipStream_t stream)
{
  const float* x    = (const float*)d_in[0];
  const float* x0   = (const float*)d_in[1];
  const float* lamR = (const float*)d_in[2];
  const float* lamX = (const float*)d_in[3];
  const float* cs   = (const float*)d_in[4];
  const float* sn   = (const float*)d_in[5];
  const float* Wq   = (const float*)d_in[6];
  const float* Wk   = (const float*)d_in[7];
  const float* Wv   = (const float*)d_in[8];
  const float* Wp   = (const float*)d_in[9];
  const float* Wfc  = (const float*)d_in[10];
  const float* Wmp  = (const float*)d_in[11];
  float* out = (float*)d_out;

  const int B = 2, T = 2048, C = 1024, H = 16;
  const int M = B * T;  // 4096
  const size_t MB = 1ull << 20;
  char* ws = (char*)d_ws;
  f16*   Wqkv_t = (f16*)(ws + 0 * MB);     // 6 MB
  f16*   Wp_t   = (f16*)(ws + 6 * MB);     // 2 MB
  f16*   Wfc_t  = (f16*)(ws + 8 * MB);     // 8 MB
  f16*   Wmp_t  = (f16*)(ws + 16 * MB);    // 8 MB
  float* scaled  = (float*)(ws + 24 * MB); // 16 MB fp32 [reused: mlp f16 partials 2x8MB]
  f16*   pre     = (f16*)(ws + 40 * MB);   // 8 MB       [reused: attnOut]
  f16*   qb      = (f16*)(ws + 48 * MB);   // 8 MB       [reused: pre2]
  f16*   kbuf    = (f16*)(ws + 56 * MB);   // 8 MB
  f16*   vtg     = (f16*)(ws + 64 * MB);   // 8 MB V^T
  float* scaled2 = (float*)(ws + 72 * MB); // 16 MB fp32
  f16*   hbuf    = (f16*)(ws + 88 * MB);   // 32 MB      [first: proj f16 partials 2x8MB]
  f16*   attnOut = pre;
  f16*   pre2    = qb;
  f16*   projP   = (f16*)(ws + 88 * MB);   // 2 x 8 MB f16 (before hbuf written)
  f16*   mlpP    = (f16*)(ws + 24 * MB);   // 2 x 8 MB f16 (scaled dead by then)

  dim3 tb(256);
  wconv_kernel<<<dim3(C/32,   C/32),   tb, 0, stream>>>(Wq,  Wqkv_t,             C,   C);
  wconv_kernel<<<dim3(C/32,   C/32),   tb, 0, stream>>>(Wk,  Wqkv_t + 1024*1024, C,   C);
  wconv_kernel<<<dim3(C/32,   C/32),   tb, 0, stream>>>(Wv,  Wqkv_t + 2048*1024, C,   C);
  wconv_kernel<<<dim3(C/32,   C/32),   tb, 0, stream>>>(Wp,  Wp_t,               C,   C);
  wconv_kernel<<<dim3(4*C/32, C/32),   tb, 0, stream>>>(Wfc, Wfc_t,              C,   4*C);
  wconv_kernel<<<dim3(C/32,   4*C/32), tb, 0, stream>>>(Wmp, Wmp_t,              4*C, C);

  scale_rms_kernel<<<M, tb, 0, stream>>>(x, x0, lamR, lamX, scaled, pre);

  // fused QKV GEMM (768 blocks, XCD-swizzled 1-D grid)
  gemm_qkv_kernel<<<dim3(24 * 32), tb, 0, stream>>>(pre, Wqkv_t, qb, kbuf, vtg);

  rope_rms_kernel<<<(M * H) / 4, tb, 0, stream>>>(qb,   cs, sn);
  rope_rms_kernel<<<(M * H) / 4, tb, 0, stream>>>(kbuf, cs, sn);

  // grid (bh, qt): bh fastest -> per-head XCD pinning
  attn_kernel<<<dim3(B * H, T/64), tb, 0, stream>>>(qb, kbuf, vtg, attnOut);

  // proj GEMM split-K=2 (512 blocks) -> f16 partials ; combine + rms
  gemm_kernel<4><<<dim3(8 * 32 * 2), tb, 0, stream>>>(attnOut, Wp_t, projP, M, C, C, 8, 2);
  combine_rms_kernel<<<M, tb, 0, stream>>>(scaled, projP, projP + (size_t)M*C, scaled2, pre2);

  // fc GEMM + relu^2 (1024 blocks)
  gemm_kernel<1><<<dim3(32 * 32), tb, 0, stream>>>(pre2, Wfc_t, hbuf, M, 4*C, C, 32, 1);

  // mlp proj split-K=2 (512 blocks) -> f16 partials ; combine into out
  gemm_kernel<4><<<dim3(8 * 32 * 2), tb, 0, stream>>>(hbuf, Wmp_t, mlpP, M, C, 4*C, 8, 2);
  combine_out_kernel<<<(M*C)/1024, tb, 0, stream>>>(scaled2, mlpP, mlpP + (size_t)M*C, out);
}

// Round 7
// 394.768 us; speedup vs baseline: 1.4059x; 1.0623x over previous
//
#include <hip/hip_runtime.h>
#include <hip/hip_bf16.h>
#include <stdint.h>

typedef _Float16 f16;
typedef __attribute__((ext_vector_type(8))) _Float16 f16x8;
typedef __attribute__((ext_vector_type(4))) _Float16 f16x4;
typedef __attribute__((ext_vector_type(4))) float f32x4;

__device__ __forceinline__ void g2l16(const void* g, void* l) {
  __builtin_amdgcn_global_load_lds(
      (const __attribute__((address_space(1))) uint32_t*)g,
      (__attribute__((address_space(3))) uint32_t*)l, 16, 0, 0);
}

// ---------------- fused weight transpose + fp32->f16 convert (all 6 weights) ----------------
__global__ __launch_bounds__(256)
void wconv_all_kernel(const float* __restrict__ Wq, const float* __restrict__ Wk,
                      const float* __restrict__ Wv, const float* __restrict__ Wp,
                      const float* __restrict__ Wfc, const float* __restrict__ Wmp,
                      f16* __restrict__ Dq, f16* __restrict__ Dk, f16* __restrict__ Dv,
                      f16* __restrict__ Dp, f16* __restrict__ Dfc, f16* __restrict__ Dmp)
{
  __shared__ float tile[32][33];
  int id = blockIdx.x;
  const float* W; f16* Wt; int K, N, local;
  if      (id < 1024) { W = Wq;  Wt = Dq;  K = 1024; N = 1024; local = id; }
  else if (id < 2048) { W = Wk;  Wt = Dk;  K = 1024; N = 1024; local = id - 1024; }
  else if (id < 3072) { W = Wv;  Wt = Dv;  K = 1024; N = 1024; local = id - 2048; }
  else if (id < 4096) { W = Wp;  Wt = Dp;  K = 1024; N = 1024; local = id - 3072; }
  else if (id < 8192) { W = Wfc; Wt = Dfc; K = 1024; N = 4096; local = id - 4096; }
  else                { W = Wmp; Wt = Dmp; K = 4096; N = 1024; local = id - 8192; }
  int ntx = N >> 5;
  int n0 = (local % ntx) * 32, k0 = (local / ntx) * 32;
  int tx = threadIdx.x & 31, ty = threadIdx.x >> 5;
#pragma unroll
  for (int i = 0; i < 4; ++i)
    tile[ty + 8*i][tx] = W[(size_t)(k0 + ty + 8*i) * N + (n0 + tx)];
  __syncthreads();
#pragma unroll
  for (int i = 0; i < 4; ++i)
    Wt[(size_t)(n0 + ty + 8*i) * K + (k0 + tx)] = (f16)tile[tx][ty + 8*i];
}

// ---------------- scaled = x*lr + x0*lx ; pre = rmsnorm(scaled) ----------------
__global__ __launch_bounds__(256)
void scale_rms_kernel(const float* __restrict__ x, const float* __restrict__ x0,
                      const float* __restrict__ lamR, const float* __restrict__ lamX,
                      float* __restrict__ scaled, f16* __restrict__ pre)
{
  const int C = 1024;
  int row = blockIdx.x, tid = threadIdx.x;
  float lr = lamR[0], lx = lamX[0];
  size_t base = (size_t)row * C;
  float4 xv = ((const float4*)(x + base))[tid];
  float4 zv = ((const float4*)(x0 + base))[tid];
  float4 sv;
  sv.x = xv.x*lr + zv.x*lx;  sv.y = xv.y*lr + zv.y*lx;
  sv.z = xv.z*lr + zv.z*lx;  sv.w = xv.w*lr + zv.w*lx;
  float ss = sv.x*sv.x + sv.y*sv.y + sv.z*sv.z + sv.w*sv.w;
#pragma unroll
  for (int off = 32; off >= 1; off >>= 1) ss += __shfl_xor(ss, off);
  __shared__ float red[4];
  if ((tid & 63) == 0) red[tid >> 6] = ss;
  __syncthreads();
  float tot = red[0] + red[1] + red[2] + red[3];
  float rs = rsqrtf(tot * (1.0f / 1024.0f) + 1e-5f);
  ((float4*)(scaled + base))[tid] = sv;
  f16* p = pre + base + tid * 4;
  p[0] = (f16)(sv.x * rs); p[1] = (f16)(sv.y * rs);
  p[2] = (f16)(sv.z * rs); p[3] = (f16)(sv.w * rs);
}

// ---------------- combine_rms: scaled2 = resid+p0+p1 (f16 partials) ; pre2 = rms ----------------
__global__ __launch_bounds__(256)
void combine_rms_kernel(const float* __restrict__ resid, const f16* __restrict__ p0,
                        const f16* __restrict__ p1, float* __restrict__ scaled2,
                        f16* __restrict__ pre2)
{
  const int C = 1024;
  int row = blockIdx.x, tid = threadIdx.x;
  size_t base = (size_t)row * C;
  float4 rv = ((const float4*)(resid + base))[tid];
  f16x4 av = ((const f16x4*)(p0 + base))[tid];
  f16x4 bv = ((const f16x4*)(p1 + base))[tid];
  float4 sv;
  sv.x = rv.x + (float)av[0] + (float)bv[0];
  sv.y = rv.y + (float)av[1] + (float)bv[1];
  sv.z = rv.z + (float)av[2] + (float)bv[2];
  sv.w = rv.w + (float)av[3] + (float)bv[3];
  float ss = sv.x*sv.x + sv.y*sv.y + sv.z*sv.z + sv.w*sv.w;
#pragma unroll
  for (int off = 32; off >= 1; off >>= 1) ss += __shfl_xor(ss, off);
  __shared__ float red[4];
  if ((tid & 63) == 0) red[tid >> 6] = ss;
  __syncthreads();
  float tot = red[0] + red[1] + red[2] + red[3];
  float rs = rsqrtf(tot * (1.0f / 1024.0f) + 1e-5f);
  ((float4*)(scaled2 + base))[tid] = sv;
  f16* p = pre2 + base + tid * 4;
  p[0] = (f16)(sv.x * rs); p[1] = (f16)(sv.y * rs);
  p[2] = (f16)(sv.z * rs); p[3] = (f16)(sv.w * rs);
}

// ---------------- combine_out: out = resid + sum of 4 f16 partials ----------------
__global__ __launch_bounds__(256)
void combine_out4_kernel(const float* __restrict__ resid, const f16* __restrict__ parts,
                         size_t pstride, float* __restrict__ out)
{
  size_t i = (size_t)blockIdx.x * 256 + threadIdx.x;
  float4 rv = ((const float4*)resid)[i];
  float4 sv = rv;
#pragma unroll
  for (int z = 0; z < 4; ++z) {
    f16x4 av = ((const f16x4*)(parts + z * pstride))[i];
    sv.x += (float)av[0]; sv.y += (float)av[1];
    sv.z += (float)av[2]; sv.w += (float)av[3];
  }
  ((float4*)out)[i] = sv;
}

// ---------------- fused RoPE + rmsnorm on q and k, (B*T, H, 64) f16 ----------------
__global__ __launch_bounds__(256)
void rope_rms_kernel(f16* __restrict__ Xq, f16* __restrict__ Xk,
                     const float* __restrict__ cs, const float* __restrict__ sn)
{
  const int MH = 4096 * 16;
  int ridx = blockIdx.x * 4 + (threadIdx.x >> 6);  // over 2*B*T*H
  f16* X = (ridx < MH) ? Xq : Xk;
  if (ridx >= MH) ridx -= MH;
  int lane = threadIdx.x & 63;
  int h = ridx & 15;
  int bt = ridx >> 4;
  int t = bt & 2047;
  size_t base = (size_t)bt * 1024 + h * 64;
  float xv = (float)X[base + lane];
  float other = __shfl_xor(xv, 32);
  float rot = (lane < 32) ? -other : other;
  float c = cs[t * 64 + lane], s = sn[t * 64 + lane];
  float y = xv * c + rot * s;
  float ss = y * y;
#pragma unroll
  for (int off = 32; off >= 1; off >>= 1) ss += __shfl_xor(ss, off);
  float r = rsqrtf(ss * (1.0f / 64.0f) + 1e-5f);
  X[base + lane] = (f16)(y * r);
}

// ---------------- GEMM: C[M,N] = A[M,K] @ Bt[N,K]^T, f16 in, fp32 acc ----------------
// XCD-aware 1-D grid (id&7 = XCD, n fastest within XCD). LDS-round-trip epilogue:
// per-wave 16x64 slab, quad-XOR on 16-col blocks (2-way max = free), b128 reads,
// dwordx4 global stores.  EPI 1: f16 relu(v)^2 ; EPI 4: f16 partial at out+zz*M*N.
template<int EPI>
__global__ __launch_bounds__(256)
void gemm_kernel(const f16* __restrict__ A, const f16* __restrict__ Bt,
                 void* __restrict__ out, int M, int N, int K, int nb, int zb)
{
  __shared__ __align__(16) f16 smem[2 * 128 * 32];
  f16* As = smem;
  f16* Bs = smem + 128 * 32;
  const int tid = threadIdx.x;
  const int wave = tid >> 6, lane = tid & 63;
  const int col = lane & 15, quad = lane >> 4;
  const int id = blockIdx.x;
  const int xcd = id & 7, s = id >> 3;
  const int n_i = s % nb;
  const int p = s / nb;
  const int mpx = (M >> 7) >> 3;
  const int zz = p / mpx;
  const int m_i = xcd * mpx + (p % mpx);
  const int m0 = m_i * 128, n0 = n_i * 128;
  const int wm = (wave >> 1) * 64, wn = (wave & 1) * 64;
  const int Ksub = K / zb;
  const int kBeg = zz * Ksub, kEnd = kBeg + Ksub;
  f32x4 acc[4][4] = {};

  const size_t rowb = (size_t)K * 2;
  const char* Agp = (const char*)A  + (size_t)m0 * rowb;
  const char* Bgp = (const char*)Bt + (size_t)n0 * rowb;

  for (int k0 = kBeg; k0 < kEnd; k0 += 32) {
#pragma unroll
    for (int i = 0; i < 2; ++i) {
      int e = i * 256 + tid;
      int r = e >> 2;
      int cb = (e & 3) << 4;
      int lbase = (i * 256 + wave * 64) << 4;
      g2l16(Agp + (size_t)r * rowb + (size_t)k0 * 2 + cb, (char*)As + lbase);
      g2l16(Bgp + (size_t)r * rowb + (size_t)k0 * 2 + cb, (char*)Bs + lbase);
    }
    __syncthreads();
    f16x8 af[4], bf[4];
#pragma unroll
    for (int t = 0; t < 4; ++t)
      af[t] = *(const f16x8*)(As + (wm + t*16 + col) * 32 + quad * 8);
#pragma unroll
    for (int t = 0; t < 4; ++t)
      bf[t] = *(const f16x8*)(Bs + (wn + t*16 + col) * 32 + quad * 8);
#pragma unroll
    for (int mt = 0; mt < 4; ++mt)
#pragma unroll
      for (int nt = 0; nt < 4; ++nt)
        acc[mt][nt] = __builtin_amdgcn_mfma_f32_16x16x32_f16(af[mt], bf[nt], acc[mt][nt], 0, 0, 0);
    __syncthreads();
  }
  // epilogue: after final barrier all waves are done with As/Bs -> reuse as per-wave slab
  f16* ep = smem + wave * 1024;   // 16 x 64 f16
  f16* outz = (EPI == 4) ? ((f16*)out + (size_t)zz * M * N) : (f16*)out;
#pragma unroll
  for (int mt = 0; mt < 4; ++mt) {
#pragma unroll
    for (int nt = 0; nt < 4; ++nt) {
#pragma unroll
      for (int r = 0; r < 4; ++r) {
        float v = acc[mt][nt][r];
        if (EPI == 1) { float tv = v > 0.0f ? v : 0.0f; v = tv * tv; }
        ep[(quad * 4 + r) * 64 + ((nt ^ quad) * 16 + col)] = (f16)v;
      }
    }
    // same-wave DS ordering: reads below see this wave's writes
#pragma unroll
    for (int j = 0; j < 2; ++j) {
      int e = j * 64 + lane;
      int row = e >> 3, rb = e & 7;
      int phys16 = (((rb >> 1) ^ (row >> 2)) << 1) + (rb & 1);
      f16x8 vv = *(const f16x8*)(ep + row * 64 + phys16 * 8);
      int grow = m0 + wm + mt * 16 + row;
      int gcol = n0 + wn + rb * 8;
      *(f16x8*)(outz + (size_t)grow * N + gcol) = vv;
    }
  }
}

// ---------------- fused QKV GEMM: A[4096,1024] @ Wqkv[3072,1024]^T ----------------
// cols 0..1023 -> qb ; 1024..2047 -> kbuf (row-major, LDS epilogue)
// cols 2048..3071 -> vtg [(b*16+h)*64+d][t]: acc regs = 4 consecutive t, same d ->
// direct f16x4 8B stores, no LDS.
__global__ __launch_bounds__(256)
void gemm_qkv_kernel(const f16* __restrict__ A, const f16* __restrict__ Bt,
                     f16* __restrict__ qb, f16* __restrict__ kbuf, f16* __restrict__ vtg)
{
  const int K = 1024, nb = 24;
  __shared__ __align__(16) f16 smem[2 * 128 * 32];
  f16* As = smem;
  f16* Bs = smem + 128 * 32;
  const int tid = threadIdx.x;
  const int wave = tid >> 6, lane = tid & 63;
  const int col = lane & 15, quad = lane >> 4;
  const int id = blockIdx.x;
  const int xcd = id & 7, s = id >> 3;
  const int n_i = s % nb;
  const int m_i = xcd * 4 + (s / nb);
  const int m0 = m_i * 128, n0 = n_i * 128;
  const int wm = (wave >> 1) * 64, wn = (wave & 1) * 64;
  f32x4 acc[4][4] = {};

  const size_t rowb = (size_t)K * 2;
  const char* Agp = (const char*)A  + (size_t)m0 * rowb;
  const char* Bgp = (const char*)Bt + (size_t)n0 * rowb;

  for (int k0 = 0; k0 < K; k0 += 32) {
#pragma unroll
    for (int i = 0; i < 2; ++i) {
      int e = i * 256 + tid;
      int r = e >> 2;
      int cb = (e & 3) << 4;
      int lbase = (i * 256 + wave * 64) << 4;
      g2l16(Agp + (size_t)r * rowb + (size_t)k0 * 2 + cb, (char*)As + lbase);
      g2l16(Bgp + (size_t)r * rowb + (size_t)k0 * 2 + cb, (char*)Bs + lbase);
    }
    __syncthreads();
    f16x8 af[4], bf[4];
#pragma unroll
    for (int t = 0; t < 4; ++t)
      af[t] = *(const f16x8*)(As + (wm + t*16 + col) * 32 + quad * 8);
#pragma unroll
    for (int t = 0; t < 4; ++t)
      bf[t] = *(const f16x8*)(Bs + (wn + t*16 + col) * 32 + quad * 8);
#pragma unroll
    for (int mt = 0; mt < 4; ++mt)
#pragma unroll
      for (int nt = 0; nt < 4; ++nt)
        acc[mt][nt] = __builtin_amdgcn_mfma_f32_16x16x32_f16(af[mt], bf[nt], acc[mt][nt], 0, 0, 0);
    __syncthreads();
  }
  const int cw = n0 + wn;           // wave's 64-col base in 0..3071
  const int sel = cw >> 10;         // 0: Q, 1: K, 2: V (wave-uniform)
  if (sel < 2) {
    f16* dst = (sel == 0) ? qb : kbuf;
    const int cbase = cw & 1023;
    f16* ep = smem + wave * 1024;
#pragma unroll
    for (int mt = 0; mt < 4; ++mt) {
#pragma unroll
      for (int nt = 0; nt < 4; ++nt)
#pragma unroll
        for (int r = 0; r < 4; ++r)
          ep[(quad * 4 + r) * 64 + ((nt ^ quad) * 16 + col)] = (f16)acc[mt][nt][r];
#pragma unroll
      for (int j = 0; j < 2; ++j) {
        int e = j * 64 + lane;
        int row = e >> 3, rb = e & 7;
        int phys16 = (((rb >> 1) ^ (row >> 2)) << 1) + (rb & 1);
        f16x8 vv = *(const f16x8*)(ep + row * 64 + phys16 * 8);
        int grow = m0 + wm + mt * 16 + row;
        *(f16x8*)(dst + (size_t)grow * 1024 + cbase + rb * 8) = vv;
      }
    }
  } else {
    // V: acc[mt][nt][0..3] are 4 consecutive t (rows), same output d -> direct 8B store
#pragma unroll
    for (int mt = 0; mt < 4; ++mt) {
      int t0 = m0 + wm + mt * 16 + quad * 4;
      int b = t0 >> 11, t = t0 & 2047;
#pragma unroll
      for (int nt = 0; nt < 4; ++nt) {
        int dd = (cw & 1023) + nt * 16 + col;   // 0..1023 -> h = dd>>6, d = dd&63
        int hh = dd >> 6, d = dd & 63;
        f16x4 vv;
#pragma unroll
        for (int r = 0; r < 4; ++r) vv[r] = (f16)acc[mt][nt][r];
        *(f16x4*)(vtg + ((size_t)((b * 16 + hh) * 64 + d)) * 2048 + t) = vv;
      }
    }
  }
}

// ---------------- causal flash attention, hd=64, no-max softmax, dbuf staging ----------------
__global__ __launch_bounds__(256)
void attn_kernel(const f16* __restrict__ Q, const f16* __restrict__ Kc,
                 const f16* __restrict__ Vt, f16* __restrict__ O)
{
  const int T = 2048, C = 1024;
  __shared__ __align__(16) f16 Ks[2][64 * 64];
  __shared__ __align__(16) f16 Vs[2][64 * 64];
  __shared__ __align__(16) f16 Ps[4][16 * 64];
  const int tid = threadIdx.x, wave = tid >> 6, lane = tid & 63;
  const int col = lane & 15, quad = lane >> 4;
  const int bh = blockIdx.x, b = bh >> 4, h = bh & 15;
  const int qt = (int)gridDim.y - 1 - (int)blockIdx.y;
  const int q0 = qt * 64;

  const f16* qb = Q  + ((size_t)b * T) * C + h * 64;
  const f16* kb = Kc + ((size_t)b * T) * C + h * 64;
  const f16* vb = Vt + ((size_t)bh * 64) * T;

  f16x8 aq[2];
#pragma unroll
  for (int ks = 0; ks < 2; ++ks)
    aq[ks] = *(const f16x8*)(qb + (size_t)(q0 + wave*16 + col) * C + ks*32 + quad*8);

  f32x4 o_acc[4];
#pragma unroll
  for (int dt = 0; dt < 4; ++dt) o_acc[dt] = (f32x4){0.f,0.f,0.f,0.f};
  float l_part[4] = {0.f, 0.f, 0.f, 0.f};

  const int srow = lane >> 3;
  const int sblk = (lane & 7) ^ srow;

#pragma unroll
  for (int i = 0; i < 2; ++i) {
    int r0 = wave * 16 + 8 * i;
    g2l16(kb + (size_t)(r0 + srow) * C + sblk * 8, (char*)Ks[0] + r0 * 128);
    g2l16(vb + (size_t)(r0 + srow) * T + sblk * 8, (char*)Vs[0] + r0 * 128);
  }

  int cur = 0;
  for (int kt = 0; kt <= qt; ++kt) {
    __syncthreads();

    if (kt < qt) {
      const int ks1 = (kt + 1) * 64;
#pragma unroll
      for (int i = 0; i < 2; ++i) {
        int r0 = wave * 16 + 8 * i;
        g2l16(kb + (size_t)(ks1 + r0 + srow) * C + sblk * 8, (char*)Ks[cur ^ 1] + r0 * 128);
        g2l16(vb + (size_t)(r0 + srow) * T + ks1 + sblk * 8, (char*)Vs[cur ^ 1] + r0 * 128);
      }
    }

    f32x4 s[4];
#pragma unroll
    for (int nt = 0; nt < 4; ++nt) s[nt] = (f32x4){0.f,0.f,0.f,0.f};
#pragma unroll
    for (int ks = 0; ks < 2; ++ks) {
#pragma unroll
      for (int nt = 0; nt < 4; ++nt) {
        int key = nt * 16 + col;
        f16x8 bk = *(const f16x8*)(Ks[cur] + key * 64 + (((ks*4 + quad) ^ (key & 7)) * 8));
        s[nt] = __builtin_amdgcn_mfma_f32_16x16x32_f16(aq[ks], bk, s[nt], 0, 0, 0);
      }
    }

    const bool masked = (kt == qt);
#pragma unroll
    for (int r = 0; r < 4; ++r) {
      const int qloc = quad * 4 + r;
      float p[4];
#pragma unroll
      for (int nt = 0; nt < 4; ++nt) {
        float pv = __expf(s[nt][r] * 0.125f);
        if (masked && (nt * 16 + col > wave * 16 + qloc)) pv = 0.0f;
        p[nt] = pv;
      }
      l_part[r] += (p[0] + p[1]) + (p[2] + p[3]);
#pragma unroll
      for (int nt = 0; nt < 4; ++nt) {
        int kblk = nt * 2 + (col >> 3);
        Ps[wave][qloc * 64 + ((kblk ^ (qloc & 7)) * 8) + (col & 7)] = (f16)p[nt];
      }
    }

#pragma unroll
    for (int ks = 0; ks < 2; ++ks) {
      f16x8 ap = *(const f16x8*)(&Ps[wave][0] + col * 64 + (((ks*4 + quad) ^ (col & 7)) * 8));
#pragma unroll
      for (int dt = 0; dt < 4; ++dt) {
        int d = dt * 16 + col;
        f16x8 bv = *(const f16x8*)(Vs[cur] + d * 64 + (((ks*4 + quad) ^ (d & 7)) * 8));
        o_acc[dt] = __builtin_amdgcn_mfma_f32_16x16x32_f16(ap, bv, o_acc[dt], 0, 0, 0);
      }
    }
    cur ^= 1;
  }

#pragma unroll
  for (int r = 0; r < 4; ++r) {
#pragma unroll
    for (int off = 8; off >= 1; off >>= 1)
      l_part[r] += __shfl_xor(l_part[r], off, 16);
  }
#pragma unroll
  for (int dt = 0; dt < 4; ++dt) {
#pragma unroll
    for (int r = 0; r < 4; ++r) {
      int qr = q0 + wave * 16 + quad * 4 + r;
      float v = o_acc[dt][r] / l_part[r];
      O[((size_t)b * T + qr) * C + h * 64 + dt * 16 + col] = (f16)v;
    }
  }
}

// ---------------- orchestration ----------------
extern "C" void kernel_launch(void* const* d_in, const int* in_sizes, int n_in,
                              void* d_out, int out_size, void* d_ws, size_t ws_size,
                              hipStream_t stream)
{
  const float* x    = (const float*)d_in[0];
  const float* x0   = (const float*)d_in[1];
  const float* lamR = (const float*)d_in[2];
  const float* lamX = (const float*)d_in[3];
  const float* cs   = (const float*)d_in[4];
  const float* sn   = (const float*)d_in[5];
  const float* Wq   = (const float*)d_in[6];
  const float* Wk   = (const float*)d_in[7];
  const float* Wv   = (const float*)d_in[8];
  const float* Wp   = (const float*)d_in[9];
  const float* Wfc  = (const float*)d_in[10];
  const float* Wmp  = (const float*)d_in[11];
  float* out = (float*)d_out;

  const int B = 2, T = 2048, C = 1024, H = 16;
  const int M = B * T;  // 4096
  const size_t MB = 1ull << 20;
  char* ws = (char*)d_ws;
  f16*   Wqkv_t = (f16*)(ws + 0 * MB);     // 6 MB
  f16*   Wp_t   = (f16*)(ws + 6 * MB);     // 2 MB
  f16*   Wfc_t  = (f16*)(ws + 8 * MB);     // 8 MB
  f16*   Wmp_t  = (f16*)(ws + 16 * MB);    // 8 MB
  float* scaled  = (float*)(ws + 24 * MB); // 16 MB fp32 [later: mlp partials z0,z1]
  f16*   pre     = (f16*)(ws + 40 * MB);   // 8 MB       [later: attnOut -> mlp partial z2]
  f16*   qb      = (f16*)(ws + 48 * MB);   // 8 MB       [later: pre2 -> mlp partial z3]
  f16*   kbuf    = (f16*)(ws + 56 * MB);   // 8 MB
  f16*   vtg     = (f16*)(ws + 64 * MB);   // 8 MB V^T
  float* scaled2 = (float*)(ws + 72 * MB); // 16 MB fp32
  f16*   hbuf    = (f16*)(ws + 88 * MB);   // 32 MB      [first: proj f16 partials 2x8MB]
  f16*   attnOut = pre;
  f16*   pre2    = qb;
  f16*   projP   = (f16*)(ws + 88 * MB);   // 2 x 8 MB f16 (before hbuf written)
  f16*   mlpP    = (f16*)(ws + 24 * MB);   // 4 x 8 MB f16 (scaled/pre/qb all dead)

  dim3 tb(256);
  wconv_all_kernel<<<dim3(12288), tb, 0, stream>>>(
      Wq, Wk, Wv, Wp, Wfc, Wmp,
      Wqkv_t, Wqkv_t + 1024*1024, Wqkv_t + 2048*1024, Wp_t, Wfc_t, Wmp_t);

  scale_rms_kernel<<<M, tb, 0, stream>>>(x, x0, lamR, lamX, scaled, pre);

  // fused QKV GEMM (768 blocks, XCD-swizzled)
  gemm_qkv_kernel<<<dim3(24 * 32), tb, 0, stream>>>(pre, Wqkv_t, qb, kbuf, vtg);

  rope_rms_kernel<<<(M * H) / 2, tb, 0, stream>>>(qb, kbuf, cs, sn);

  // grid (bh, qt): bh fastest -> per-head XCD pinning
  attn_kernel<<<dim3(B * H, T/64), tb, 0, stream>>>(qb, kbuf, vtg, attnOut);

  // proj GEMM split-K=2 (512 blocks) -> f16 partials ; combine + rms
  gemm_kernel<4><<<dim3(8 * 32 * 2), tb, 0, stream>>>(attnOut, Wp_t, projP, M, C, C, 8, 2);
  combine_rms_kernel<<<M, tb, 0, stream>>>(scaled, projP, projP + (size_t)M*C, scaled2, pre2);

  // fc GEMM + relu^2 (1024 blocks)
  gemm_kernel<1><<<dim3(32 * 32), tb, 0, stream>>>(pre2, Wfc_t, hbuf, M, 4*C, C, 32, 1);

  // mlp proj split-K=4 (1024 blocks) -> f16 partials ; combine into out
  gemm_kernel<4><<<dim3(8 * 32 * 4), tb, 0, stream>>>(hbuf, Wmp_t, mlpP, M, C, 4*C, 8, 4);
  combine_out4_kernel<<<(M*C)/1024, tb, 0, stream>>>(scaled2, mlpP, (size_t)M*C, out);
}

// Round 9
// 379.922 us; speedup vs baseline: 1.4608x; 1.0391x over previous
//
#include <hip/hip_runtime.h>
#include <hip/hip_bf16.h>
#include <stdint.h>

typedef _Float16 f16;
typedef __attribute__((ext_vector_type(8))) _Float16 f16x8;
typedef __attribute__((ext_vector_type(4))) _Float16 f16x4;
typedef __attribute__((ext_vector_type(4))) float f32x4;

__device__ __forceinline__ void g2l16(const void* g, void* l) {
  __builtin_amdgcn_global_load_lds(
      (const __attribute__((address_space(1))) uint32_t*)g,
      (__attribute__((address_space(3))) uint32_t*)l, 16, 0, 0);
}

// ---------------- fused weight transpose + fp32->f16 convert (all 6 weights) ----------------
__global__ __launch_bounds__(256)
void wconv_all_kernel(const float* __restrict__ Wq, const float* __restrict__ Wk,
                      const float* __restrict__ Wv, const float* __restrict__ Wp,
                      const float* __restrict__ Wfc, const float* __restrict__ Wmp,
                      f16* __restrict__ Dq, f16* __restrict__ Dk, f16* __restrict__ Dv,
                      f16* __restrict__ Dp, f16* __restrict__ Dfc, f16* __restrict__ Dmp)
{
  __shared__ float tile[32][33];
  int id = blockIdx.x;
  const float* W; f16* Wt; int K, N, local;
  if      (id < 1024) { W = Wq;  Wt = Dq;  K = 1024; N = 1024; local = id; }
  else if (id < 2048) { W = Wk;  Wt = Dk;  K = 1024; N = 1024; local = id - 1024; }
  else if (id < 3072) { W = Wv;  Wt = Dv;  K = 1024; N = 1024; local = id - 2048; }
  else if (id < 4096) { W = Wp;  Wt = Dp;  K = 1024; N = 1024; local = id - 3072; }
  else if (id < 8192) { W = Wfc; Wt = Dfc; K = 1024; N = 4096; local = id - 4096; }
  else                { W = Wmp; Wt = Dmp; K = 4096; N = 1024; local = id - 8192; }
  int ntx = N >> 5;
  int n0 = (local % ntx) * 32, k0 = (local / ntx) * 32;
  int tx = threadIdx.x & 31, ty = threadIdx.x >> 5;
#pragma unroll
  for (int i = 0; i < 4; ++i)
    tile[ty + 8*i][tx] = W[(size_t)(k0 + ty + 8*i) * N + (n0 + tx)];
  __syncthreads();
#pragma unroll
  for (int i = 0; i < 4; ++i)
    Wt[(size_t)(n0 + ty + 8*i) * K + (k0 + tx)] = (f16)tile[tx][ty + 8*i];
}

// ---------------- scaled = x*lr + x0*lx ; pre = rmsnorm(scaled) ----------------
__global__ __launch_bounds__(256)
void scale_rms_kernel(const float* __restrict__ x, const float* __restrict__ x0,
                      const float* __restrict__ lamR, const float* __restrict__ lamX,
                      float* __restrict__ scaled, f16* __restrict__ pre)
{
  const int C = 1024;
  int row = blockIdx.x, tid = threadIdx.x;
  float lr = lamR[0], lx = lamX[0];
  size_t base = (size_t)row * C;
  float4 xv = ((const float4*)(x + base))[tid];
  float4 zv = ((const float4*)(x0 + base))[tid];
  float4 sv;
  sv.x = xv.x*lr + zv.x*lx;  sv.y = xv.y*lr + zv.y*lx;
  sv.z = xv.z*lr + zv.z*lx;  sv.w = xv.w*lr + zv.w*lx;
  float ss = sv.x*sv.x + sv.y*sv.y + sv.z*sv.z + sv.w*sv.w;
#pragma unroll
  for (int off = 32; off >= 1; off >>= 1) ss += __shfl_xor(ss, off);
  __shared__ float red[4];
  if ((tid & 63) == 0) red[tid >> 6] = ss;
  __syncthreads();
  float tot = red[0] + red[1] + red[2] + red[3];
  float rs = rsqrtf(tot * (1.0f / 1024.0f) + 1e-5f);
  ((float4*)(scaled + base))[tid] = sv;
  f16* p = pre + base + tid * 4;
  p[0] = (f16)(sv.x * rs); p[1] = (f16)(sv.y * rs);
  p[2] = (f16)(sv.z * rs); p[3] = (f16)(sv.w * rs);
}

// ---------------- combine_rms: scaled2 = resid+p0+p1 (f16 partials) ; pre2 = rms ----------------
__global__ __launch_bounds__(256)
void combine_rms_kernel(const float* __restrict__ resid, const f16* __restrict__ p0,
                        const f16* __restrict__ p1, float* __restrict__ scaled2,
                        f16* __restrict__ pre2)
{
  const int C = 1024;
  int row = blockIdx.x, tid = threadIdx.x;
  size_t base = (size_t)row * C;
  float4 rv = ((const float4*)(resid + base))[tid];
  f16x4 av = ((const f16x4*)(p0 + base))[tid];
  f16x4 bv = ((const f16x4*)(p1 + base))[tid];
  float4 sv;
  sv.x = rv.x + (float)av[0] + (float)bv[0];
  sv.y = rv.y + (float)av[1] + (float)bv[1];
  sv.z = rv.z + (float)av[2] + (float)bv[2];
  sv.w = rv.w + (float)av[3] + (float)bv[3];
  float ss = sv.x*sv.x + sv.y*sv.y + sv.z*sv.z + sv.w*sv.w;
#pragma unroll
  for (int off = 32; off >= 1; off >>= 1) ss += __shfl_xor(ss, off);
  __shared__ float red[4];
  if ((tid & 63) == 0) red[tid >> 6] = ss;
  __syncthreads();
  float tot = red[0] + red[1] + red[2] + red[3];
  float rs = rsqrtf(tot * (1.0f / 1024.0f) + 1e-5f);
  ((float4*)(scaled2 + base))[tid] = sv;
  f16* p = pre2 + base + tid * 4;
  p[0] = (f16)(sv.x * rs); p[1] = (f16)(sv.y * rs);
  p[2] = (f16)(sv.z * rs); p[3] = (f16)(sv.w * rs);
}

// ---------------- combine_out: out = resid + sum of 4 f16 partials ----------------
__global__ __launch_bounds__(256)
void combine_out4_kernel(const float* __restrict__ resid, const f16* __restrict__ parts,
                         size_t pstride, float* __restrict__ out)
{
  size_t i = (size_t)blockIdx.x * 256 + threadIdx.x;
  float4 rv = ((const float4*)resid)[i];
  float4 sv = rv;
#pragma unroll
  for (int z = 0; z < 4; ++z) {
    f16x4 av = ((const f16x4*)(parts + z * pstride))[i];
    sv.x += (float)av[0]; sv.y += (float)av[1];
    sv.z += (float)av[2]; sv.w += (float)av[3];
  }
  ((float4*)out)[i] = sv;
}

// ---------------- fused RoPE + rmsnorm on q and k, (B*T, H, 64) f16 ----------------
__global__ __launch_bounds__(256)
void rope_rms_kernel(f16* __restrict__ Xq, f16* __restrict__ Xk,
                     const float* __restrict__ cs, const float* __restrict__ sn)
{
  const int MH = 4096 * 16;
  int ridx = blockIdx.x * 4 + (threadIdx.x >> 6);  // over 2*B*T*H
  f16* X = (ridx < MH) ? Xq : Xk;
  if (ridx >= MH) ridx -= MH;
  int lane = threadIdx.x & 63;
  int h = ridx & 15;
  int bt = ridx >> 4;
  int t = bt & 2047;
  size_t base = (size_t)bt * 1024 + h * 64;
  float xv = (float)X[base + lane];
  float other = __shfl_xor(xv, 32);
  float rot = (lane < 32) ? -other : other;
  float c = cs[t * 64 + lane], s = sn[t * 64 + lane];
  float y = xv * c + rot * s;
  float ss = y * y;
#pragma unroll
  for (int off = 32; off >= 1; off >>= 1) ss += __shfl_xor(ss, off);
  float r = rsqrtf(ss * (1.0f / 64.0f) + 1e-5f);
  X[base + lane] = (f16)(y * r);
}

// ---------------- GEMM: C[M,N] = A[M,K] @ Bt[N,K]^T, f16 in, fp32 acc ----------------
// XCD-aware 1-D grid; DOUBLE-BUFFERED K-loop: prefetch tile k+1 right after the
// barrier publishing tile k. LDS 32 KB (2x(As+Bs)).  Iteration counts are even, so
// the last tile is always in buf1 -> epilogue slab reuses buf0 safely.
// EPI 1: f16 relu(v)^2 ; EPI 4: f16 partial at out+zz*M*N.
template<int EPI>
__global__ __launch_bounds__(256)
void gemm_kernel(const f16* __restrict__ A, const f16* __restrict__ Bt,
                 void* __restrict__ out, int M, int N, int K, int nb, int zb)
{
  __shared__ __align__(16) f16 smem[4 * 128 * 32];   // As0|As1|Bs0|Bs1
  const int tid = threadIdx.x;
  const int wave = tid >> 6, lane = tid & 63;
  const int col = lane & 15, quad = lane >> 4;
  const int id = blockIdx.x;
  const int xcd = id & 7, s = id >> 3;
  const int n_i = s % nb;
  const int p = s / nb;
  const int mpx = (M >> 7) >> 3;
  const int zz = p / mpx;
  const int m_i = xcd * mpx + (p % mpx);
  const int m0 = m_i * 128, n0 = n_i * 128;
  const int wm = (wave >> 1) * 64, wn = (wave & 1) * 64;
  const int Ksub = K / zb;
  const int kBeg = zz * Ksub;
  const int nIter = Ksub >> 5;
  f32x4 acc[4][4] = {};

  const size_t rowb = (size_t)K * 2;
  const char* Agp = (const char*)A  + (size_t)m0 * rowb;
  const char* Bgp = (const char*)Bt + (size_t)n0 * rowb;

  const int r_st = (tid >> 2);
  const int cb_st = (tid & 3) << 4;
  const int lb0 = (wave * 64) << 4;
  const int lb1 = (256 + wave * 64) << 4;

#define STAGE(buf, k0)                                                           \
  {                                                                              \
    const size_t koff = (size_t)(k0) * 2;                                        \
    g2l16(Agp + (size_t)r_st * rowb + koff + cb_st,                              \
          (char*)smem + (buf) * 8192 + lb0);                                     \
    g2l16(Agp + (size_t)(r_st + 64) * rowb + koff + cb_st,                       \
          (char*)smem + (buf) * 8192 + lb1);                                     \
    g2l16(Bgp + (size_t)r_st * rowb + koff + cb_st,                              \
          (char*)smem + 16384 + (buf) * 8192 + lb0);                             \
    g2l16(Bgp + (size_t)(r_st + 64) * rowb + koff + cb_st,                       \
          (char*)smem + 16384 + (buf) * 8192 + lb1);                             \
  }

  STAGE(0, kBeg)
  for (int kt = 0; kt < nIter; ++kt) {
    __syncthreads();   // prefetched buf[kt&1] complete; all waves done with buf[kt&1^1]
    if (kt + 1 < nIter) STAGE((kt + 1) & 1, kBeg + (kt + 1) * 32)
    const f16* As = smem + (kt & 1) * 4096;
    const f16* Bs = smem + 8192 + (kt & 1) * 4096;
    f16x8 af[4], bf[4];
#pragma unroll
    for (int t = 0; t < 4; ++t)
      af[t] = *(const f16x8*)(As + (wm + t*16 + col) * 32 + quad * 8);
#pragma unroll
    for (int t = 0; t < 4; ++t)
      bf[t] = *(const f16x8*)(Bs + (wn + t*16 + col) * 32 + quad * 8);
#pragma unroll
    for (int mt = 0; mt < 4; ++mt)
#pragma unroll
      for (int nt = 0; nt < 4; ++nt)
        acc[mt][nt] = __builtin_amdgcn_mfma_f32_16x16x32_f16(af[mt], bf[nt], acc[mt][nt], 0, 0, 0);
  }
#undef STAGE
  // epilogue: last tile was buf1 (nIter even) -> buf0 region free for slabs
  f16* ep = smem + wave * 1024;   // 16 x 64 f16 per wave, within As buf0
  f16* outz = (EPI == 4) ? ((f16*)out + (size_t)zz * M * N) : (f16*)out;
#pragma unroll
  for (int mt = 0; mt < 4; ++mt) {
#pragma unroll
    for (int nt = 0; nt < 4; ++nt) {
#pragma unroll
      for (int r = 0; r < 4; ++r) {
        float v = acc[mt][nt][r];
        if (EPI == 1) { float tv = v > 0.0f ? v : 0.0f; v = tv * tv; }
        ep[(quad * 4 + r) * 64 + ((nt ^ quad) * 16 + col)] = (f16)v;
      }
    }
#pragma unroll
    for (int j = 0; j < 2; ++j) {
      int e = j * 64 + lane;
      int row = e >> 3, rb = e & 7;
      int phys16 = (((rb >> 1) ^ (row >> 2)) << 1) + (rb & 1);
      f16x8 vv = *(const f16x8*)(ep + row * 64 + phys16 * 8);
      int grow = m0 + wm + mt * 16 + row;
      int gcol = n0 + wn + rb * 8;
      *(f16x8*)(outz + (size_t)grow * N + gcol) = vv;
    }
  }
}

// ---------------- fused QKV GEMM: A[4096,1024] @ Wqkv[3072,1024]^T ----------------
// Double-buffered K-loop. Q/K via LDS epilogue; V direct f16x4 transposed stores.
__global__ __launch_bounds__(256)
void gemm_qkv_kernel(const f16* __restrict__ A, const f16* __restrict__ Bt,
                     f16* __restrict__ qb, f16* __restrict__ kbuf, f16* __restrict__ vtg)
{
  const int K = 1024, nb = 24;
  __shared__ __align__(16) f16 smem[4 * 128 * 32];
  const int tid = threadIdx.x;
  const int wave = tid >> 6, lane = tid & 63;
  const int col = lane & 15, quad = lane >> 4;
  const int id = blockIdx.x;
  const int xcd = id & 7, s = id >> 3;
  const int n_i = s % nb;
  const int m_i = xcd * 4 + (s / nb);
  const int m0 = m_i * 128, n0 = n_i * 128;
  const int wm = (wave >> 1) * 64, wn = (wave & 1) * 64;
  f32x4 acc[4][4] = {};

  const size_t rowb = (size_t)K * 2;
  const char* Agp = (const char*)A  + (size_t)m0 * rowb;
  const char* Bgp = (const char*)Bt + (size_t)n0 * rowb;

  const int r_st = (tid >> 2);
  const int cb_st = (tid & 3) << 4;
  const int lb0 = (wave * 64) << 4;
  const int lb1 = (256 + wave * 64) << 4;

#define STAGE(buf, k0)                                                           \
  {                                                                              \
    const size_t koff = (size_t)(k0) * 2;                                        \
    g2l16(Agp + (size_t)r_st * rowb + koff + cb_st,                              \
          (char*)smem + (buf) * 8192 + lb0);                                     \
    g2l16(Agp + (size_t)(r_st + 64) * rowb + koff + cb_st,                       \
          (char*)smem + (buf) * 8192 + lb1);                                     \
    g2l16(Bgp + (size_t)r_st * rowb + koff + cb_st,                              \
          (char*)smem + 16384 + (buf) * 8192 + lb0);                             \
    g2l16(Bgp + (size_t)(r_st + 64) * rowb + koff + cb_st,                       \
          (char*)smem + 16384 + (buf) * 8192 + lb1);                             \
  }

  STAGE(0, 0)
  for (int kt = 0; kt < 32; ++kt) {
    __syncthreads();
    if (kt + 1 < 32) STAGE((kt + 1) & 1, (kt + 1) * 32)
    const f16* As = smem + (kt & 1) * 4096;
    const f16* Bs = smem + 8192 + (kt & 1) * 4096;
    f16x8 af[4], bf[4];
#pragma unroll
    for (int t = 0; t < 4; ++t)
      af[t] = *(const f16x8*)(As + (wm + t*16 + col) * 32 + quad * 8);
#pragma unroll
    for (int t = 0; t < 4; ++t)
      bf[t] = *(const f16x8*)(Bs + (wn + t*16 + col) * 32 + quad * 8);
#pragma unroll
    for (int mt = 0; mt < 4; ++mt)
#pragma unroll
      for (int nt = 0; nt < 4; ++nt)
        acc[mt][nt] = __builtin_amdgcn_mfma_f32_16x16x32_f16(af[mt], bf[nt], acc[mt][nt], 0, 0, 0);
  }
#undef STAGE
  const int cw = n0 + wn;           // wave's 64-col base in 0..3071
  const int sel = cw >> 10;         // 0: Q, 1: K, 2: V (wave-uniform)
  if (sel < 2) {
    f16* dst = (sel == 0) ? qb : kbuf;
    const int cbase = cw & 1023;
    f16* ep = smem + wave * 1024;
#pragma unroll
    for (int mt = 0; mt < 4; ++mt) {
#pragma unroll
      for (int nt = 0; nt < 4; ++nt)
#pragma unroll
        for (int r = 0; r < 4; ++r)
          ep[(quad * 4 + r) * 64 + ((nt ^ quad) * 16 + col)] = (f16)acc[mt][nt][r];
#pragma unroll
      for (int j = 0; j < 2; ++j) {
        int e = j * 64 + lane;
        int row = e >> 3, rb = e & 7;
        int phys16 = (((rb >> 1) ^ (row >> 2)) << 1) + (rb & 1);
        f16x8 vv = *(const f16x8*)(ep + row * 64 + phys16 * 8);
        int grow = m0 + wm + mt * 16 + row;
        *(f16x8*)(dst + (size_t)grow * 1024 + cbase + rb * 8) = vv;
      }
    }
  } else {
    // V: acc[mt][nt][0..3] are 4 consecutive t (rows), same output d -> direct 8B store
#pragma unroll
    for (int mt = 0; mt < 4; ++mt) {
      int t0 = m0 + wm + mt * 16 + quad * 4;
      int b = t0 >> 11, t = t0 & 2047;
#pragma unroll
      for (int nt = 0; nt < 4; ++nt) {
        int dd = (cw & 1023) + nt * 16 + col;   // 0..1023 -> h = dd>>6, d = dd&63
        int hh = dd >> 6, d = dd & 63;
        f16x4 vv;
#pragma unroll
        for (int r = 0; r < 4; ++r) vv[r] = (f16)acc[mt][nt][r];
        *(f16x4*)(vtg + ((size_t)((b * 16 + hh) * 64 + d)) * 2048 + t) = vv;
      }
    }
  }
}

// ---------------- causal flash attention, hd=64, no-max softmax, dbuf staging ----------------
__global__ __launch_bounds__(256)
void attn_kernel(const f16* __restrict__ Q, const f16* __restrict__ Kc,
                 const f16* __restrict__ Vt, f16* __restrict__ O)
{
  const int T = 2048, C = 1024;
  __shared__ __align__(16) f16 Ks[2][64 * 64];
  __shared__ __align__(16) f16 Vs[2][64 * 64];
  __shared__ __align__(16) f16 Ps[4][16 * 64];
  const int tid = threadIdx.x, wave = tid >> 6, lane = tid & 63;
  const int col = lane & 15, quad = lane >> 4;
  const int bh = blockIdx.x, b = bh >> 4, h = bh & 15;
  const int qt = (int)gridDim.y - 1 - (int)blockIdx.y;
  const int q0 = qt * 64;

  const f16* qb = Q  + ((size_t)b * T) * C + h * 64;
  const f16* kb = Kc + ((size_t)b * T) * C + h * 64;
  const f16* vb = Vt + ((size_t)bh * 64) * T;

  f16x8 aq[2];
#pragma unroll
  for (int ks = 0; ks < 2; ++ks)
    aq[ks] = *(const f16x8*)(qb + (size_t)(q0 + wave*16 + col) * C + ks*32 + quad*8);

  f32x4 o_acc[4];
#pragma unroll
  for (int dt = 0; dt < 4; ++dt) o_acc[dt] = (f32x4){0.f,0.f,0.f,0.f};
  float l_part[4] = {0.f, 0.f, 0.f, 0.f};

  const int srow = lane >> 3;
  const int sblk = (lane & 7) ^ srow;

#pragma unroll
  for (int i = 0; i < 2; ++i) {
    int r0 = wave * 16 + 8 * i;
    g2l16(kb + (size_t)(r0 + srow) * C + sblk * 8, (char*)Ks[0] + r0 * 128);
    g2l16(vb + (size_t)(r0 + srow) * T + sblk * 8, (char*)Vs[0] + r0 * 128);
  }

  int cur = 0;
  for (int kt = 0; kt <= qt; ++kt) {
    __syncthreads();

    if (kt < qt) {
      const int ks1 = (kt + 1) * 64;
#pragma unroll
      for (int i = 0; i < 2; ++i) {
        int r0 = wave * 16 + 8 * i;
        g2l16(kb + (size_t)(ks1 + r0 + srow) * C + sblk * 8, (char*)Ks[cur ^ 1] + r0 * 128);
        g2l16(vb + (size_t)(r0 + srow) * T + ks1 + sblk * 8, (char*)Vs[cur ^ 1] + r0 * 128);
      }
    }

    f32x4 s[4];
#pragma unroll
    for (int nt = 0; nt < 4; ++nt) s[nt] = (f32x4){0.f,0.f,0.f,0.f};
#pragma unroll
    for (int ks = 0; ks < 2; ++ks) {
#pragma unroll
      for (int nt = 0; nt < 4; ++nt) {
        int key = nt * 16 + col;
        f16x8 bk = *(const f16x8*)(Ks[cur] + key * 64 + (((ks*4 + quad) ^ (key & 7)) * 8));
        s[nt] = __builtin_amdgcn_mfma_f32_16x16x32_f16(aq[ks], bk, s[nt], 0, 0, 0);
      }
    }

    const bool masked = (kt == qt);
#pragma unroll
    for (int r = 0; r < 4; ++r) {
      const int qloc = quad * 4 + r;
      float p[4];
#pragma unroll
      for (int nt = 0; nt < 4; ++nt) {
        float pv = __expf(s[nt][r] * 0.125f);
        if (masked && (nt * 16 + col > wave * 16 + qloc)) pv = 0.0f;
        p[nt] = pv;
      }
      l_part[r] += (p[0] + p[1]) + (p[2] + p[3]);
#pragma unroll
      for (int nt = 0; nt < 4; ++nt) {
        int kblk = nt * 2 + (col >> 3);
        Ps[wave][qloc * 64 + ((kblk ^ (qloc & 7)) * 8) + (col & 7)] = (f16)p[nt];
      }
    }

#pragma unroll
    for (int ks = 0; ks < 2; ++ks) {
      f16x8 ap = *(const f16x8*)(&Ps[wave][0] + col * 64 + (((ks*4 + quad) ^ (col & 7)) * 8));
#pragma unroll
      for (int dt = 0; dt < 4; ++dt) {
        int d = dt * 16 + col;
        f16x8 bv = *(const f16x8*)(Vs[cur] + d * 64 + (((ks*4 + quad) ^ (d & 7)) * 8));
        o_acc[dt] = __builtin_amdgcn_mfma_f32_16x16x32_f16(ap, bv, o_acc[dt], 0, 0, 0);
      }
    }
    cur ^= 1;
  }

#pragma unroll
  for (int r = 0; r < 4; ++r) {
#pragma unroll
    for (int off = 8; off >= 1; off >>= 1)
      l_part[r] += __shfl_xor(l_part[r], off, 16);
  }
#pragma unroll
  for (int dt = 0; dt < 4; ++dt) {
#pragma unroll
    for (int r = 0; r < 4; ++r) {
      int qr = q0 + wave * 16 + quad * 4 + r;
      float v = o_acc[dt][r] / l_part[r];
      O[((size_t)b * T + qr) * C + h * 64 + dt * 16 + col] = (f16)v;
    }
  }
}

// ---------------- orchestration ----------------
extern "C" void kernel_launch(void* const* d_in, const int* in_sizes, int n_in,
                              void* d_out, int out_size, void* d_ws, size_t ws_size,
                              hipStream_t stream)
{
  const float* x    = (const float*)d_in[0];
  const float* x0   = (const float*)d_in[1];
  const float* lamR = (const float*)d_in[2];
  const float* lamX = (const float*)d_in[3];
  const float* cs   = (const float*)d_in[4];
  const float* sn   = (const float*)d_in[5];
  const float* Wq   = (const float*)d_in[6];
  const float* Wk   = (const float*)d_in[7];
  const float* Wv   = (const float*)d_in[8];
  const float* Wp   = (const float*)d_in[9];
  const float* Wfc  = (const float*)d_in[10];
  const float* Wmp  = (const float*)d_in[11];
  float* out = (float*)d_out;

  const int B = 2, T = 2048, C = 1024, H = 16;
  const int M = B * T;  // 4096
  const size_t MB = 1ull << 20;
  char* ws = (char*)d_ws;
  f16*   Wqkv_t = (f16*)(ws + 0 * MB);     // 6 MB
  f16*   Wp_t   = (f16*)(ws + 6 * MB);     // 2 MB
  f16*   Wfc_t  = (f16*)(ws + 8 * MB);     // 8 MB
  f16*   Wmp_t  = (f16*)(ws + 16 * MB);    // 8 MB
  float* scaled  = (float*)(ws + 24 * MB); // 16 MB fp32 [later: mlp partials z0,z1]
  f16*   pre     = (f16*)(ws + 40 * MB);   // 8 MB       [later: attnOut -> mlp partial z2]
  f16*   qb      = (f16*)(ws + 48 * MB);   // 8 MB       [later: pre2 -> mlp partial z3]
  f16*   kbuf    = (f16*)(ws + 56 * MB);   // 8 MB
  f16*   vtg     = (f16*)(ws + 64 * MB);   // 8 MB V^T
  float* scaled2 = (float*)(ws + 72 * MB); // 16 MB fp32
  f16*   hbuf    = (f16*)(ws + 88 * MB);   // 32 MB      [first: proj f16 partials 2x8MB]
  f16*   attnOut = pre;
  f16*   pre2    = qb;
  f16*   projP   = (f16*)(ws + 88 * MB);   // 2 x 8 MB f16 (before hbuf written)
  f16*   mlpP    = (f16*)(ws + 24 * MB);   // 4 x 8 MB f16 (scaled/pre/qb all dead)

  dim3 tb(256);
  wconv_all_kernel<<<dim3(12288), tb, 0, stream>>>(
      Wq, Wk, Wv, Wp, Wfc, Wmp,
      Wqkv_t, Wqkv_t + 1024*1024, Wqkv_t + 2048*1024, Wp_t, Wfc_t, Wmp_t);

  scale_rms_kernel<<<M, tb, 0, stream>>>(x, x0, lamR, lamX, scaled, pre);

  // fused QKV GEMM (768 blocks, XCD-swizzled, dbuf)
  gemm_qkv_kernel<<<dim3(24 * 32), tb, 0, stream>>>(pre, Wqkv_t, qb, kbuf, vtg);

  rope_rms_kernel<<<(M * H) / 2, tb, 0, stream>>>(qb, kbuf, cs, sn);

  // grid (bh, qt): bh fastest -> per-head XCD pinning
  attn_kernel<<<dim3(B * H, T/64), tb, 0, stream>>>(qb, kbuf, vtg, attnOut);

  // proj GEMM split-K=2 (512 blocks) -> f16 partials ; combine + rms
  gemm_kernel<4><<<dim3(8 * 32 * 2), tb, 0, stream>>>(attnOut, Wp_t, projP, M, C, C, 8, 2);
  combine_rms_kernel<<<M, tb, 0, stream>>>(scaled, projP, projP + (size_t)M*C, scaled2, pre2);

  // fc GEMM + relu^2 (1024 blocks, dbuf)
  gemm_kernel<1><<<dim3(32 * 32), tb, 0, stream>>>(pre2, Wfc_t, hbuf, M, 4*C, C, 32, 1);

  // mlp proj split-K=4 (1024 blocks) -> f16 partials ; combine into out
  gemm_kernel<4><<<dim3(8 * 32 * 4), tb, 0, stream>>>(hbuf, Wmp_t, mlpP, M, C, 4*C, 8, 4);
  combine_out4_kernel<<<(M*C)/1024, tb, 0, stream>>>(scaled2, mlpP, (size_t)M*C, out);
}